// Round 2
// baseline (1070.356 us; speedup 1.0000x reference)
//
#include <hip/hip_runtime.h>
#include <hip/hip_bf16.h>

typedef __hip_bfloat16 bf16;
typedef __attribute__((ext_vector_type(8))) short short8;
typedef __attribute__((ext_vector_type(4))) float f32x4;

#define S_LEN 512
#define DIM   512
#define BATCH 128
#define ROWS  (BATCH * S_LEN)

__device__ inline unsigned short f2bu(float f){
    bf16 h = __float2bfloat16(f);
    return *reinterpret_cast<unsigned short*>(&h);
}
__device__ inline float ld_in(const void* p, size_t i, int f32){
    return f32 ? ((const float*)p)[i] : __bfloat162float(((const bf16*)p)[i]);
}

// async global->LDS, 16B per lane; LDS dest = wave-uniform base + lane*16
typedef __attribute__((address_space(1))) const unsigned int gu32;
typedef __attribute__((address_space(3))) unsigned int lu32;
__device__ __forceinline__ void gld16(const void* g, void* l){
    __builtin_amdgcn_global_load_lds((gu32*)g, (lu32*)l, 16, 0, 0);
}

// ---------------------------------------------------------------------------
// dtype detector (unchanged)
// ---------------------------------------------------------------------------
__global__ void detect_dtype(const unsigned int* __restrict__ x, int* __restrict__ flag)
{
    __shared__ int cnt;
    if (threadIdx.x == 0) cnt = 0;
    __syncthreads();
    int loc = 0;
    for (int i = threadIdx.x; i < 8192; i += 256)
        if (((x[i] >> 7) & 0xFFu) == 0xFFu) loc++;
    atomicAdd(&cnt, loc);
    __syncthreads();
    if (threadIdx.x == 0) *flag = (cnt > 0) ? 1 : 0;
}

// ---------------------------------------------------------------------------
// converters (unchanged)
// ---------------------------------------------------------------------------
__global__ void conv_tr(const void* __restrict__ in, bf16* __restrict__ outp,
                        const int* __restrict__ flagp)
{
    const int f32 = *flagp;
    __shared__ unsigned short tile[32][33];
    const int bx = blockIdx.x, by = blockIdx.y;
    const int tx = threadIdx.x, ty = threadIdx.y;   // 32 x 8
    #pragma unroll
    for (int j = 0; j < 32; j += 8)
        tile[ty + j][tx] = f2bu(ld_in(in, (size_t)(by*32 + ty + j)*DIM + bx*32 + tx, f32));
    __syncthreads();
    #pragma unroll
    for (int j = 0; j < 32; j += 8) {
        unsigned short u = tile[tx][ty + j];
        outp[(size_t)(bx*32 + ty + j)*DIM + by*32 + tx] = *reinterpret_cast<bf16*>(&u);
    }
}

__global__ void conv_cp(const void* __restrict__ in, bf16* __restrict__ outp,
                        const int* __restrict__ flagp)
{
    const int f32 = *flagp;
    const size_t i = (size_t)blockIdx.x*256 + threadIdx.x;
    outp[i] = __float2bfloat16(ld_in(in, i, f32));
}

// x (any dtype) -> bf16, 8 elems/thread, chunk at element offset eoff
__global__ void conv_x(const void* __restrict__ X, size_t eoff, bf16* __restrict__ xb,
                       const int* __restrict__ flagp)
{
    const int f32 = *flagp;
    const size_t i = ((size_t)blockIdx.x*256 + threadIdx.x)*8;
    if (f32) {
        const float* p = (const float*)X + eoff + i;
        float4 a = *(const float4*)p;
        float4 b = *(const float4*)(p + 4);
        __align__(16) unsigned short wv[8];
        wv[0]=f2bu(a.x); wv[1]=f2bu(a.y); wv[2]=f2bu(a.z); wv[3]=f2bu(a.w);
        wv[4]=f2bu(b.x); wv[5]=f2bu(b.y); wv[6]=f2bu(b.z); wv[7]=f2bu(b.w);
        *(uint4*)(xb + i) = *(const uint4*)wv;
    } else {
        *(uint4*)(xb + i) = *(const uint4*)((const bf16*)X + eoff + i);
    }
}

// ---------------------------------------------------------------------------
// dvec[n] = sum_k bv[k]*WoT[n][k] + bo[n]; bvec[n] = dvec[n] + bi[n]
// ---------------------------------------------------------------------------
__global__ void cvec_kernel(const bf16* __restrict__ WoT, const void* __restrict__ bv,
                            const void* __restrict__ bo, const void* __restrict__ bi,
                            const int* __restrict__ flagp,
                            float* __restrict__ dvec, float* __restrict__ bvec)
{
    const int f32 = *flagp;
    const int n = blockIdx.x * 4 + (threadIdx.x >> 6);
    const int lane = threadIdx.x & 63;
    float acc = 0.f;
    for (int k = lane; k < DIM; k += 64)
        acc += ld_in(bv, k, f32) * __bfloat162float(WoT[(size_t)n*DIM + k]);
    #pragma unroll
    for (int o = 32; o > 0; o >>= 1) acc += __shfl_down(acc, o, 64);
    if (lane == 0) {
        const float dd = acc + ld_in(bo, n, f32);
        dvec[n] = dd;
        bvec[n] = dd + ld_in(bi, n, f32);
    }
}

// special A rows for the big passes: A1[b]=bf16(U0[b]-d), V0b=bf16(V0), Zr=0
__global__ void prep_aux(const float* __restrict__ U0, const float* __restrict__ V0,
                         const float* __restrict__ dvec,
                         bf16* __restrict__ A1, bf16* __restrict__ V0b, bf16* __restrict__ Zr)
{
    const int idx = blockIdx.x * 256 + threadIdx.x;     // 65536
    const int n = idx & 511;
    A1[idx]  = __float2bfloat16(U0[idx] - dvec[n]);
    V0b[idx] = __float2bfloat16(V0[idx]);
    if (idx < 512) Zr[idx] = __float2bfloat16(0.f);
}

// ---------------------------------------------------------------------------
// Old padded-LDS tile core (kept for the small setup GEMMs)
// ---------------------------------------------------------------------------
#define TILE_PROLOGUE                                                          \
    __shared__ __align__(16) unsigned short As[128][72];                       \
    __shared__ __align__(16) unsigned short Bs[128][72];                       \
    const int tid  = threadIdx.x;                                              \
    const int lane = tid & 63;                                                 \
    const int wave = tid >> 6;                                                 \
    const int wm = (wave & 1) * 64;                                            \
    const int wn = (wave >> 1) * 64;                                           \
    const int cn = lane & 15;                                                  \
    const int quad = lane >> 4;                                                \
    f32x4 acc[4][4];                                                           \
    _Pragma("unroll")                                                          \
    for (int i = 0; i < 4; ++i)                                                \
        _Pragma("unroll")                                                      \
        for (int j = 0; j < 4; ++j) acc[i][j] = (f32x4){0.f,0.f,0.f,0.f};

#define TILE_MFMA                                                              \
        __syncthreads();                                                       \
        _Pragma("unroll")                                                      \
        for (int ks = 0; ks < 64; ks += 32) {                                  \
            short8 af[4], bfr[4];                                              \
            const int koff = ks + quad*8;                                      \
            _Pragma("unroll")                                                  \
            for (int i = 0; i < 4; ++i) af[i]  = *(const short8*)&As[wm + i*16 + cn][koff]; \
            _Pragma("unroll")                                                  \
            for (int j = 0; j < 4; ++j) bfr[j] = *(const short8*)&Bs[wn + j*16 + cn][koff]; \
            _Pragma("unroll")                                                  \
            for (int i = 0; i < 4; ++i)                                        \
                _Pragma("unroll")                                              \
                for (int j = 0; j < 4; ++j)                                    \
                    acc[i][j] = __builtin_amdgcn_mfma_f32_16x16x32_bf16(af[i], bfr[j], acc[i][j], 0, 0, 0); \
        }                                                                      \
        __syncthreads();

#define STAGE_B(Bt, C0)                                                        \
        {                                                                      \
            int r = tid >> 3; const int c = (tid & 7) * 8;                     \
            _Pragma("unroll")                                                  \
            for (int p = 0; p < 4; ++p, r += 32) {                             \
                uint4 v = *(const uint4*)((Bt) + (size_t)((C0) + r)*DIM + k0 + c); \
                *(uint4*)&Bs[r][c] = v;                                        \
            }                                                                  \
        }

#define STAGE_A_IN(SRC, BASE)                                                  \
                if (f32) {                                                     \
                    const float* sp = (const float*)(SRC) + (BASE);            \
                    float4 a = *(const float4*)sp;                             \
                    float4 b = *(const float4*)(sp + 4);                       \
                    __align__(16) unsigned short w[8];                         \
                    w[0]=f2bu(a.x); w[1]=f2bu(a.y); w[2]=f2bu(a.z); w[3]=f2bu(a.w); \
                    w[4]=f2bu(b.x); w[5]=f2bu(b.y); w[6]=f2bu(b.z); w[7]=f2bu(b.w); \
                    *(uint4*)&As[r][c] = *(const uint4*)w;                     \
                } else {                                                       \
                    *(uint4*)&As[r][c] = *(const uint4*)((const bf16*)(SRC) + (BASE)); \
                }

// ---------------------------------------------------------------------------
// gemm_sq / gemm_row0 / gemm_v0 (unchanged small setup GEMMs)
// ---------------------------------------------------------------------------
__global__ __launch_bounds__(256) void gemm_sq(const bf16* __restrict__ A,
        const bf16* __restrict__ Btm, bf16* __restrict__ Pout, bf16* __restrict__ Tout)
{
    TILE_PROLOGUE
    const int R0 = blockIdx.y * 128;
    const int C0 = blockIdx.x * 128;
    for (int k0 = 0; k0 < DIM; k0 += 64) {
        {
            int r = tid >> 3; const int c = (tid & 7) * 8;
            #pragma unroll
            for (int p = 0; p < 4; ++p, r += 32)
                *(uint4*)&As[r][c] = *(const uint4*)(A + (size_t)(R0 + r)*DIM + k0 + c);
        }
        STAGE_B(Btm, C0)
        TILE_MFMA
    }
    #pragma unroll
    for (int i = 0; i < 4; ++i) {
        const int rowb = R0 + wm + i*16 + quad*4;
        #pragma unroll
        for (int j = 0; j < 4; ++j) {
            const int cc = C0 + wn + j*16 + cn;
            #pragma unroll
            for (int rr = 0; rr < 4; ++rr) {
                const float v = acc[i][j][rr];
                Pout[(size_t)(rowb + rr)*DIM + cc] = __float2bfloat16(v);
                Tout[(size_t)cc*DIM + rowb + rr]  = __float2bfloat16(v);
            }
        }
    }
}

__global__ __launch_bounds__(256) void gemm_row0(const void* __restrict__ X,
        const bf16* __restrict__ WiT, const float* __restrict__ bvec,
        const int* __restrict__ flagp, float* __restrict__ U0)
{
    const int f32 = *flagp;
    TILE_PROLOGUE
    const int C0 = blockIdx.x * 128;
    for (int k0 = 0; k0 < DIM; k0 += 64) {
        {
            int r = tid >> 3; const int c = (tid & 7) * 8;
            #pragma unroll
            for (int p = 0; p < 4; ++p, r += 32) {
                const size_t base = (size_t)r*S_LEN*DIM + k0 + c;
                STAGE_A_IN(X, base)
            }
        }
        STAGE_B(WiT, C0)
        TILE_MFMA
    }
    #pragma unroll
    for (int i = 0; i < 4; ++i) {
        const int rowb = wm + i*16 + quad*4;
        #pragma unroll
        for (int j = 0; j < 4; ++j) {
            const int cc = C0 + wn + j*16 + cn;
            const float bb = bvec[cc];
            #pragma unroll
            for (int rr = 0; rr < 4; ++rr)
                U0[(size_t)(rowb + rr)*DIM + cc] = acc[i][j][rr] + bb;
        }
    }
}

__global__ __launch_bounds__(256) void gemm_v0(const float* __restrict__ U0,
        const bf16* __restrict__ T0, const float* __restrict__ dvec, float* __restrict__ V0)
{
    TILE_PROLOGUE
    const int C0 = blockIdx.x * 128;
    for (int k0 = 0; k0 < DIM; k0 += 64) {
        {
            int r = tid >> 3; const int c = (tid & 7) * 8;
            #pragma unroll
            for (int p = 0; p < 4; ++p, r += 32) {
                __align__(16) unsigned short w[8];
                #pragma unroll
                for (int q = 0; q < 8; ++q)
                    w[q] = f2bu(U0[(size_t)r*DIM + k0 + c + q] - dvec[k0 + c + q]);
                *(uint4*)&As[r][c] = *(const uint4*)w;
            }
        }
        STAGE_B(T0, C0)
        TILE_MFMA
    }
    #pragma unroll
    for (int i = 0; i < 4; ++i) {
        const int rowb = wm + i*16 + quad*4;
        #pragma unroll
        for (int j = 0; j < 4; ++j) {
            const int cc = C0 + wn + j*16 + cn;
            #pragma unroll
            for (int rr = 0; rr < 4; ++rr) {
                const size_t off = (size_t)(rowb + rr)*DIM + cc;
                V0[off] = acc[i][j][rr] + U0[off];
            }
        }
    }
}

// ---------------------------------------------------------------------------
// gemm_big: the 5 large passes. T3 minimum-2-phase: double-buffered LDS,
// tile t+1's global_load_lds issued BEFORE tile t's compute, ONE
// vmcnt(0)+barrier (__syncthreads) per K-step. Load latency hides under
// ds_read+MFMA of the current tile.
// MODE 2: xf pass  — A = Abf[row], residual = Rf[cc] (bvec)
// MODE 1: level 1  — t==0 -> A1[b], t==1 -> V0b[b], else Abf[row-1]; resid Rf[off]
// MODE 0: level s  — t>=shift -> Abf[row-shift] else Zr; resid Rf[off]
// Output: fp32 Of + bf16 Ob (dual store), or d_out via flag when TO_OUT.
// ---------------------------------------------------------------------------
template<int MODE, bool TO_OUT>
__global__ __launch_bounds__(256, 2) void gemm_big(
        const bf16* __restrict__ Abf, const bf16* __restrict__ A1,
        const bf16* __restrict__ V0b, const bf16* __restrict__ Zr,
        const bf16* __restrict__ Bt,  const float* __restrict__ Rf,
        float* __restrict__ Of, bf16* __restrict__ Ob,
        void* __restrict__ Oout, size_t eoff, const int* __restrict__ flagp,
        const int shift)
{
    __shared__ __align__(16) unsigned short As[2][128*64];
    __shared__ __align__(16) unsigned short Bs[2][128*64];
    const int tid  = threadIdx.x;
    const int lane = tid & 63;
    const int w    = tid >> 6;
    // XCD-grouped decode: the 4 bx sharing an A-panel land on one XCD's L2
    const int nb = gridDim.x;                       // 4*RT, RT>=4 -> nb%8==0
    const int p0 = blockIdx.x;
    const int L  = (p0 & 7) * (nb >> 3) + (p0 >> 3);
    const int bx = L & 3, by = L >> 2;
    const int R0 = by * 128, C0 = bx * 128;
    const int wm = (w & 1) * 64;
    const int wn = (w >> 1) * 64;
    const int cn = lane & 15;
    const int quad = lane >> 4;
    f32x4 acc[4][4];
    #pragma unroll
    for (int i = 0; i < 4; ++i)
        #pragma unroll
        for (int j = 0; j < 4; ++j) acc[i][j] = (f32x4){0.f,0.f,0.f,0.f};

    // per-lane source row pointers (4 staging segments per wave)
    const int lr = lane >> 3;            // row within 8-row segment
    const int lc = (lane & 7) * 8;       // element column of this lane's 16B
    const bf16* ab[4];
    const bf16* bb[4];
    #pragma unroll
    for (int p = 0; p < 4; ++p) {
        const int seg  = w*4 + p;        // 0..15
        const int r    = seg*8 + lr;     // 0..127
        const int grow = R0 + r;
        const bf16* a;
        if (MODE == 2) {
            a = Abf + (size_t)grow*DIM;
        } else if (MODE == 1) {
            const int t = grow & (S_LEN - 1);
            if      (t == 0) a = A1  + (size_t)(grow >> 9)*DIM;
            else if (t == 1) a = V0b + (size_t)(grow >> 9)*DIM;
            else             a = Abf + (size_t)(grow - 1)*DIM;
        } else {
            const int t = grow & (S_LEN - 1);
            a = (t >= shift) ? (Abf + (size_t)(grow - shift)*DIM) : Zr;
        }
        ab[p] = a + lc;
        bb[p] = Bt + (size_t)(C0 + r)*DIM + lc;
    }

    // prologue: stage K-tile 0 into buffer 0
    #pragma unroll
    for (int p = 0; p < 4; ++p) {
        const int seg = w*4 + p;
        gld16(ab[p], &As[0][seg*512]);
        gld16(bb[p], &Bs[0][seg*512]);
    }
    __syncthreads();

    #pragma unroll
    for (int k0 = 0; k0 < DIM; k0 += 64) {
        const int cur = (k0 >> 6) & 1;
        // issue next K-tile's loads first (latency hides under compute below)
        if (k0 + 64 < DIM) {
            #pragma unroll
            for (int p = 0; p < 4; ++p) {
                const int seg = w*4 + p;
                gld16(ab[p] + k0 + 64, &As[cur ^ 1][seg*512]);
                gld16(bb[p] + k0 + 64, &Bs[cur ^ 1][seg*512]);
            }
        }
        // compute current K-tile from buffer cur
        #pragma unroll
        for (int ks = 0; ks < 64; ks += 32) {
            short8 af[4], bfr[4];
            const int koff = ks + quad*8;
            #pragma unroll
            for (int i = 0; i < 4; ++i) af[i]  = *(const short8*)&As[cur][(wm + i*16 + cn)*64 + koff];
            #pragma unroll
            for (int j = 0; j < 4; ++j) bfr[j] = *(const short8*)&Bs[cur][(wn + j*16 + cn)*64 + koff];
            #pragma unroll
            for (int i = 0; i < 4; ++i)
                #pragma unroll
                for (int j = 0; j < 4; ++j)
                    acc[i][j] = __builtin_amdgcn_mfma_f32_16x16x32_bf16(af[i], bfr[j], acc[i][j], 0, 0, 0);
        }
        // one barrier per K-step: drains next-tile loads (vmcnt 0) and
        // guarantees all waves finished reading buf[cur] before reuse
        __syncthreads();
    }

    const int f32o = TO_OUT ? *flagp : 0;
    #pragma unroll
    for (int i = 0; i < 4; ++i) {
        const int rowb = R0 + wm + i*16 + quad*4;
        #pragma unroll
        for (int j = 0; j < 4; ++j) {
            const int cc = C0 + wn + j*16 + cn;
            #pragma unroll
            for (int rr = 0; rr < 4; ++rr) {
                const size_t off = (size_t)(rowb + rr)*DIM + cc;
                const float res = (MODE == 2) ? Rf[cc] : Rf[off];
                const float v = acc[i][j][rr] + res;
                if (TO_OUT) {
                    if (f32o) ((float*)Oout)[eoff + off] = v;
                    else      ((bf16*)Oout)[eoff + off]  = __float2bfloat16(v);
                } else {
                    Of[off] = v;
                    Ob[off] = __float2bfloat16(v);
                }
            }
        }
    }
}

// final_state[b,:] = outputs[b, len_b - 1, :]
__global__ void gather_final(void* __restrict__ out, const int* __restrict__ lens,
                             const int* __restrict__ flagp)
{
    const int f32 = *flagp;
    const int idx = blockIdx.x * 256 + threadIdx.x;
    const int b = idx >> 9, n = idx & 511;
    int L = lens[b];
    if (L < 1) L = 1;
    if (L > S_LEN) L = S_LEN;
    const size_t src = ((size_t)b*S_LEN + (L - 1))*DIM + n;
    const size_t dst = (size_t)ROWS*DIM + idx;
    if (f32) ((float*)out)[dst] = ((const float*)out)[src];
    else     ((bf16*)out)[dst]  = ((const bf16*)out)[src];
}

// ---------------------------------------------------------------------------
extern "C" void kernel_launch(void* const* d_in, const int* in_sizes, int n_in,
                              void* d_out, int out_size, void* d_ws, size_t ws_size,
                              hipStream_t stream)
{
    const void* X  = d_in[0];
    const void* Wi = d_in[1];
    const void* bi = d_in[2];
    // d_in[3..6] = Wq, bq, Wk, bk — dead (softmax over singleton axis == 1)
    const void* Wv = d_in[7];
    const void* bv = d_in[8];
    const void* Wo = d_in[9];
    const void* bo = d_in[10];
    const int* lens = (const int*)d_in[11];
    char* ws = (char*)d_ws;

    // ---- fixed workspace layout ----
    const size_t MATB = (size_t)DIM * DIM * sizeof(bf16);    // 524288
    bf16* WiT = (bf16*)(ws + 0*MATB);
    bf16* WoT = (bf16*)(ws + 1*MATB);
    bf16* Wvb = (bf16*)(ws + 2*MATB);
    bf16* S2  = (bf16*)(ws + 3*MATB);   // W, then W^4
    bf16* S3  = (bf16*)(ws + 4*MATB);   // W^2, then W^8
    bf16* T0  = (bf16*)(ws + 5*MATB);   // W^T
    bf16* T1  = (bf16*)(ws + 6*MATB);   // (W^2)^T
    bf16* T2  = (bf16*)(ws + 7*MATB);   // (W^4)^T
    bf16* T3  = (bf16*)(ws + 8*MATB);   // (W^8)^T
    size_t off = 9*MATB;
    float* dvec = (float*)(ws + off); off += 2048;
    float* bvec = (float*)(ws + off); off += 2048;
    int*   flag = (int*)  (ws + off); off += 256;
    float* U0   = (float*)(ws + off); off += (size_t)BATCH*DIM*4;  // 262144
    float* V0   = (float*)(ws + off); off += (size_t)BATCH*DIM*4;
    bf16*  A1   = (bf16*) (ws + off); off += (size_t)BATCH*DIM*2;  // 131072
    bf16*  V0b  = (bf16*) (ws + off); off += (size_t)BATCH*DIM*2;
    bf16*  Zr   = (bf16*) (ws + off); off += 1024;
    off = (off + 1023) & ~(size_t)1023;
    char* dyn = ws + off;
    const size_t avail = ws_size > off ? ws_size - off : 0;

    // per-chunk: xbf (CR*1024) + Uf (CR*2048) + Ub (CR*1024) + Vf (CR*2048) + Vb (CR*1024)
    int CR = 512;
    for (long cr = 65536; cr >= 512; cr >>= 1)
        if ((size_t)cr * 7168 <= avail) { CR = (int)cr; break; }

    bf16*  xbf = (bf16*) dyn;
    float* Uf  = (float*)(dyn + (size_t)CR*1024);
    bf16*  Ub  = (bf16*) (dyn + (size_t)CR*3072);
    float* Vf  = (float*)(dyn + (size_t)CR*4096);
    bf16*  Vb  = (bf16*) (dyn + (size_t)CR*6144);

    detect_dtype<<<1, 256, 0, stream>>>((const unsigned int*)X, flag);
    conv_tr<<<dim3(16,16), dim3(32,8), 0, stream>>>(Wi, WiT, flag);
    conv_tr<<<dim3(16,16), dim3(32,8), 0, stream>>>(Wo, WoT, flag);
    conv_cp<<<1024, 256, 0, stream>>>(Wv, Wvb, flag);
    cvec_kernel<<<128, 256, 0, stream>>>(WoT, bv, bo, bi, flag, dvec, bvec);
    gemm_sq<<<dim3(4,4), 256, 0, stream>>>(Wvb, WoT, S2, T0);   // W
    gemm_sq<<<dim3(4,4), 256, 0, stream>>>(S2, T0, S3, T1);     // W^2
    gemm_sq<<<dim3(4,4), 256, 0, stream>>>(S3, T1, S2, T2);     // W^4
    gemm_sq<<<dim3(4,4), 256, 0, stream>>>(S2, T2, S3, T3);     // W^8
    gemm_row0<<<dim3(4,1), 256, 0, stream>>>(X, WiT, bvec, flag, U0);
    gemm_v0<<<dim3(4,1), 256, 0, stream>>>(U0, T0, dvec, V0);
    prep_aux<<<256, 256, 0, stream>>>(U0, V0, dvec, A1, V0b, Zr);

    const int NC = ROWS / CR;
    const int RT = CR / 128;
    const int nb = 4 * RT;
    for (int c = 0; c < NC; ++c) {
        const size_t eoff = (size_t)c*CR*DIM;
        const size_t boff = (size_t)(c*(CR/S_LEN))*DIM;
        conv_x<<<CR/4, 256, 0, stream>>>(X, eoff, xbf, flag);
        gemm_big<2,false><<<nb, 256, 0, stream>>>(xbf, nullptr, nullptr, Zr,
                WiT, bvec, Uf, Ub, nullptr, 0, flag, 0);
        gemm_big<1,false><<<nb, 256, 0, stream>>>(Ub, A1 + boff, V0b + boff, Zr,
                T0, Uf, Vf, Vb, nullptr, 0, flag, 1);
        gemm_big<0,false><<<nb, 256, 0, stream>>>(Vb, nullptr, nullptr, Zr,
                T1, Vf, Uf, Ub, nullptr, 0, flag, 2);
        gemm_big<0,false><<<nb, 256, 0, stream>>>(Ub, nullptr, nullptr, Zr,
                T2, Uf, Vf, Vb, nullptr, 0, flag, 4);
        gemm_big<0,true ><<<nb, 256, 0, stream>>>(Vb, nullptr, nullptr, Zr,
                T3, Vf, nullptr, nullptr, d_out, eoff, flag, 8);
    }
    gather_final<<<256, 256, 0, stream>>>(d_out, lens, flag);
}

// Round 3
// 1016.076 us; speedup vs baseline: 1.0534x; 1.0534x over previous
//
#include <hip/hip_runtime.h>
#include <hip/hip_bf16.h>

typedef __hip_bfloat16 bf16;
typedef __attribute__((ext_vector_type(8))) short short8;
typedef __attribute__((ext_vector_type(4))) float f32x4;

#define S_LEN 512
#define DIM   512
#define BATCH 128
#define ROWS  (BATCH * S_LEN)

__device__ inline unsigned short f2bu(float f){
    bf16 h = __float2bfloat16(f);
    return *reinterpret_cast<unsigned short*>(&h);
}
__device__ inline float ld_in(const void* p, size_t i, int f32){
    return f32 ? ((const float*)p)[i] : __bfloat162float(((const bf16*)p)[i]);
}

// async global->LDS, 16B per lane; LDS dest = wave-uniform base + lane*16
typedef __attribute__((address_space(1))) const unsigned int gu32;
typedef __attribute__((address_space(3))) unsigned int lu32;
__device__ __forceinline__ void gld16(const void* g, void* l){
    __builtin_amdgcn_global_load_lds((gu32*)g, (lu32*)l, 16, 0, 0);
}

// swizzled LDS fragment read: byte = (row*128 + koff*2) ^ ((row&7)<<4)
// (matches the pre-swizzled global source column permutation at stage time)
__device__ __forceinline__ short8 lds_frag(const unsigned short* base, int row, int koff){
    const unsigned off = ((unsigned)(row*128 + koff*2)) ^ (((unsigned)(row & 7)) << 4);
    return *(const short8*)((const char*)base + off);
}

// ---------------------------------------------------------------------------
// dtype detector (unchanged)
// ---------------------------------------------------------------------------
__global__ void detect_dtype(const unsigned int* __restrict__ x, int* __restrict__ flag)
{
    __shared__ int cnt;
    if (threadIdx.x == 0) cnt = 0;
    __syncthreads();
    int loc = 0;
    for (int i = threadIdx.x; i < 8192; i += 256)
        if (((x[i] >> 7) & 0xFFu) == 0xFFu) loc++;
    atomicAdd(&cnt, loc);
    __syncthreads();
    if (threadIdx.x == 0) *flag = (cnt > 0) ? 1 : 0;
}

// ---------------------------------------------------------------------------
// converters (unchanged)
// ---------------------------------------------------------------------------
__global__ void conv_tr(const void* __restrict__ in, bf16* __restrict__ outp,
                        const int* __restrict__ flagp)
{
    const int f32 = *flagp;
    __shared__ unsigned short tile[32][33];
    const int bx = blockIdx.x, by = blockIdx.y;
    const int tx = threadIdx.x, ty = threadIdx.y;   // 32 x 8
    #pragma unroll
    for (int j = 0; j < 32; j += 8)
        tile[ty + j][tx] = f2bu(ld_in(in, (size_t)(by*32 + ty + j)*DIM + bx*32 + tx, f32));
    __syncthreads();
    #pragma unroll
    for (int j = 0; j < 32; j += 8) {
        unsigned short u = tile[tx][ty + j];
        outp[(size_t)(bx*32 + ty + j)*DIM + by*32 + tx] = *reinterpret_cast<bf16*>(&u);
    }
}

__global__ void conv_cp(const void* __restrict__ in, bf16* __restrict__ outp,
                        const int* __restrict__ flagp)
{
    const int f32 = *flagp;
    const size_t i = (size_t)blockIdx.x*256 + threadIdx.x;
    outp[i] = __float2bfloat16(ld_in(in, i, f32));
}

// x (any dtype) -> bf16, 8 elems/thread, chunk at element offset eoff
__global__ void conv_x(const void* __restrict__ X, size_t eoff, bf16* __restrict__ xb,
                       const int* __restrict__ flagp)
{
    const int f32 = *flagp;
    const size_t i = ((size_t)blockIdx.x*256 + threadIdx.x)*8;
    if (f32) {
        const float* p = (const float*)X + eoff + i;
        float4 a = *(const float4*)p;
        float4 b = *(const float4*)(p + 4);
        __align__(16) unsigned short wv[8];
        wv[0]=f2bu(a.x); wv[1]=f2bu(a.y); wv[2]=f2bu(a.z); wv[3]=f2bu(a.w);
        wv[4]=f2bu(b.x); wv[5]=f2bu(b.y); wv[6]=f2bu(b.z); wv[7]=f2bu(b.w);
        *(uint4*)(xb + i) = *(const uint4*)wv;
    } else {
        *(uint4*)(xb + i) = *(const uint4*)((const bf16*)X + eoff + i);
    }
}

// ---------------------------------------------------------------------------
// dvec[n] = sum_k bv[k]*WoT[n][k] + bo[n]; bvec[n] = dvec[n] + bi[n]
// ---------------------------------------------------------------------------
__global__ void cvec_kernel(const bf16* __restrict__ WoT, const void* __restrict__ bv,
                            const void* __restrict__ bo, const void* __restrict__ bi,
                            const int* __restrict__ flagp,
                            float* __restrict__ dvec, float* __restrict__ bvec)
{
    const int f32 = *flagp;
    const int n = blockIdx.x * 4 + (threadIdx.x >> 6);
    const int lane = threadIdx.x & 63;
    float acc = 0.f;
    for (int k = lane; k < DIM; k += 64)
        acc += ld_in(bv, k, f32) * __bfloat162float(WoT[(size_t)n*DIM + k]);
    #pragma unroll
    for (int o = 32; o > 0; o >>= 1) acc += __shfl_down(acc, o, 64);
    if (lane == 0) {
        const float dd = acc + ld_in(bo, n, f32);
        dvec[n] = dd;
        bvec[n] = dd + ld_in(bi, n, f32);
    }
}

// special A rows for the big passes: A1[b]=bf16(U0[b]-d), V0b=bf16(V0), Zr=0
__global__ void prep_aux(const float* __restrict__ U0, const float* __restrict__ V0,
                         const float* __restrict__ dvec,
                         bf16* __restrict__ A1, bf16* __restrict__ V0b, bf16* __restrict__ Zr)
{
    const int idx = blockIdx.x * 256 + threadIdx.x;     // 65536
    const int n = idx & 511;
    A1[idx]  = __float2bfloat16(U0[idx] - dvec[n]);
    V0b[idx] = __float2bfloat16(V0[idx]);
    if (idx < 512) Zr[idx] = __float2bfloat16(0.f);
}

// ---------------------------------------------------------------------------
// Old padded-LDS tile core (kept for the small setup GEMMs)
// ---------------------------------------------------------------------------
#define TILE_PROLOGUE                                                          \
    __shared__ __align__(16) unsigned short As[128][72];                       \
    __shared__ __align__(16) unsigned short Bs[128][72];                       \
    const int tid  = threadIdx.x;                                              \
    const int lane = tid & 63;                                                 \
    const int wave = tid >> 6;                                                 \
    const int wm = (wave & 1) * 64;                                            \
    const int wn = (wave >> 1) * 64;                                           \
    const int cn = lane & 15;                                                  \
    const int quad = lane >> 4;                                                \
    f32x4 acc[4][4];                                                           \
    _Pragma("unroll")                                                          \
    for (int i = 0; i < 4; ++i)                                                \
        _Pragma("unroll")                                                      \
        for (int j = 0; j < 4; ++j) acc[i][j] = (f32x4){0.f,0.f,0.f,0.f};

#define TILE_MFMA                                                              \
        __syncthreads();                                                       \
        _Pragma("unroll")                                                      \
        for (int ks = 0; ks < 64; ks += 32) {                                  \
            short8 af[4], bfr[4];                                              \
            const int koff = ks + quad*8;                                      \
            _Pragma("unroll")                                                  \
            for (int i = 0; i < 4; ++i) af[i]  = *(const short8*)&As[wm + i*16 + cn][koff]; \
            _Pragma("unroll")                                                  \
            for (int j = 0; j < 4; ++j) bfr[j] = *(const short8*)&Bs[wn + j*16 + cn][koff]; \
            _Pragma("unroll")                                                  \
            for (int i = 0; i < 4; ++i)                                        \
                _Pragma("unroll")                                              \
                for (int j = 0; j < 4; ++j)                                    \
                    acc[i][j] = __builtin_amdgcn_mfma_f32_16x16x32_bf16(af[i], bfr[j], acc[i][j], 0, 0, 0); \
        }                                                                      \
        __syncthreads();

#define STAGE_B(Bt, C0)                                                        \
        {                                                                      \
            int r = tid >> 3; const int c = (tid & 7) * 8;                     \
            _Pragma("unroll")                                                  \
            for (int p = 0; p < 4; ++p, r += 32) {                             \
                uint4 v = *(const uint4*)((Bt) + (size_t)((C0) + r)*DIM + k0 + c); \
                *(uint4*)&Bs[r][c] = v;                                        \
            }                                                                  \
        }

#define STAGE_A_IN(SRC, BASE)                                                  \
                if (f32) {                                                     \
                    const float* sp = (const float*)(SRC) + (BASE);            \
                    float4 a = *(const float4*)sp;                             \
                    float4 b = *(const float4*)(sp + 4);                       \
                    __align__(16) unsigned short w[8];                         \
                    w[0]=f2bu(a.x); w[1]=f2bu(a.y); w[2]=f2bu(a.z); w[3]=f2bu(a.w); \
                    w[4]=f2bu(b.x); w[5]=f2bu(b.y); w[6]=f2bu(b.z); w[7]=f2bu(b.w); \
                    *(uint4*)&As[r][c] = *(const uint4*)w;                     \
                } else {                                                       \
                    *(uint4*)&As[r][c] = *(const uint4*)((const bf16*)(SRC) + (BASE)); \
                }

// ---------------------------------------------------------------------------
// gemm_sq / gemm_row0 / gemm_v0 (unchanged small setup GEMMs)
// ---------------------------------------------------------------------------
__global__ __launch_bounds__(256) void gemm_sq(const bf16* __restrict__ A,
        const bf16* __restrict__ Btm, bf16* __restrict__ Pout, bf16* __restrict__ Tout)
{
    TILE_PROLOGUE
    const int R0 = blockIdx.y * 128;
    const int C0 = blockIdx.x * 128;
    for (int k0 = 0; k0 < DIM; k0 += 64) {
        {
            int r = tid >> 3; const int c = (tid & 7) * 8;
            #pragma unroll
            for (int p = 0; p < 4; ++p, r += 32)
                *(uint4*)&As[r][c] = *(const uint4*)(A + (size_t)(R0 + r)*DIM + k0 + c);
        }
        STAGE_B(Btm, C0)
        TILE_MFMA
    }
    #pragma unroll
    for (int i = 0; i < 4; ++i) {
        const int rowb = R0 + wm + i*16 + quad*4;
        #pragma unroll
        for (int j = 0; j < 4; ++j) {
            const int cc = C0 + wn + j*16 + cn;
            #pragma unroll
            for (int rr = 0; rr < 4; ++rr) {
                const float v = acc[i][j][rr];
                Pout[(size_t)(rowb + rr)*DIM + cc] = __float2bfloat16(v);
                Tout[(size_t)cc*DIM + rowb + rr]  = __float2bfloat16(v);
            }
        }
    }
}

__global__ __launch_bounds__(256) void gemm_row0(const void* __restrict__ X,
        const bf16* __restrict__ WiT, const float* __restrict__ bvec,
        const int* __restrict__ flagp, float* __restrict__ U0)
{
    const int f32 = *flagp;
    TILE_PROLOGUE
    const int C0 = blockIdx.x * 128;
    for (int k0 = 0; k0 < DIM; k0 += 64) {
        {
            int r = tid >> 3; const int c = (tid & 7) * 8;
            #pragma unroll
            for (int p = 0; p < 4; ++p, r += 32) {
                const size_t base = (size_t)r*S_LEN*DIM + k0 + c;
                STAGE_A_IN(X, base)
            }
        }
        STAGE_B(WiT, C0)
        TILE_MFMA
    }
    #pragma unroll
    for (int i = 0; i < 4; ++i) {
        const int rowb = wm + i*16 + quad*4;
        #pragma unroll
        for (int j = 0; j < 4; ++j) {
            const int cc = C0 + wn + j*16 + cn;
            const float bb = bvec[cc];
            #pragma unroll
            for (int rr = 0; rr < 4; ++rr)
                U0[(size_t)(rowb + rr)*DIM + cc] = acc[i][j][rr] + bb;
        }
    }
}

__global__ __launch_bounds__(256) void gemm_v0(const float* __restrict__ U0,
        const bf16* __restrict__ T0, const float* __restrict__ dvec, float* __restrict__ V0)
{
    TILE_PROLOGUE
    const int C0 = blockIdx.x * 128;
    for (int k0 = 0; k0 < DIM; k0 += 64) {
        {
            int r = tid >> 3; const int c = (tid & 7) * 8;
            #pragma unroll
            for (int p = 0; p < 4; ++p, r += 32) {
                __align__(16) unsigned short w[8];
                #pragma unroll
                for (int q = 0; q < 8; ++q)
                    w[q] = f2bu(U0[(size_t)r*DIM + k0 + c + q] - dvec[k0 + c + q]);
                *(uint4*)&As[r][c] = *(const uint4*)w;
            }
        }
        STAGE_B(T0, C0)
        TILE_MFMA
    }
    #pragma unroll
    for (int i = 0; i < 4; ++i) {
        const int rowb = wm + i*16 + quad*4;
        #pragma unroll
        for (int j = 0; j < 4; ++j) {
            const int cc = C0 + wn + j*16 + cn;
            #pragma unroll
            for (int rr = 0; rr < 4; ++rr) {
                const size_t off = (size_t)(rowb + rr)*DIM + cc;
                V0[off] = acc[i][j][rr] + U0[off];
            }
        }
    }
}

// ---------------------------------------------------------------------------
// gemm_big: 8-phase-style schedule (4 phases per K-tile of 64), counted vmcnt,
// both-sides st-swizzled LDS, T5 setprio.
// Stage lines (4KB = 32 rows x 64 cols): order per tile [A0,A2,B0,B2,A1,A3,B1,B3],
// 2 lines issued per phase for tile kt+1 into buf^1. Derived waits: vmcnt(4)
// before the closing barrier of phases 0,1,3 (FIFO positions guarantee the
// next phase's lines have landed across ALL waves before their ds_reads).
// Phase q=(mq,nq) consumes A-lines {mq, mq+2}, B-lines {nq, nq+2} only.
// MODE 2: xf pass — A = Abf[row], residual = Rf[cc] (bvec)
// MODE 1: level 1 — t==0 -> A1[b], t==1 -> V0b[b], else Abf[row-1]; resid Rf[off]
// MODE 0: level s — t>=shift -> Abf[row-shift] else Zr; resid Rf[off]
// ---------------------------------------------------------------------------
template<int MODE, bool TO_OUT>
__global__ __launch_bounds__(256, 2) void gemm_big(
        const bf16* __restrict__ Abf, const bf16* __restrict__ A1,
        const bf16* __restrict__ V0b, const bf16* __restrict__ Zr,
        const bf16* __restrict__ Bt,  const float* __restrict__ Rf,
        float* __restrict__ Of, bf16* __restrict__ Ob,
        void* __restrict__ Oout, size_t eoff, const int* __restrict__ flagp,
        const int shift)
{
    __shared__ __align__(16) unsigned short As[2][128*64];
    __shared__ __align__(16) unsigned short Bs[2][128*64];
    const int tid  = threadIdx.x;
    const int lane = tid & 63;
    const int w    = tid >> 6;
    // XCD-grouped decode: the 4 bx sharing an A-panel land on one XCD's L2
    const int nb = gridDim.x;                       // 4*RT, RT>=4 -> nb%8==0
    const int p0 = blockIdx.x;
    const int L  = (p0 & 7) * (nb >> 3) + (p0 >> 3);
    const int bx = L & 3, by = L >> 2;
    const int R0 = by * 128, C0 = bx * 128;
    const int wm = (w & 1) * 64;
    const int wn = (w >> 1) * 64;
    const int cn = lane & 15;
    const int quad = lane >> 4;
    f32x4 acc[4][4];
    #pragma unroll
    for (int i = 0; i < 4; ++i)
        #pragma unroll
        for (int j = 0; j < 4; ++j) acc[i][j] = (f32x4){0.f,0.f,0.f,0.f};

    // staging: line l covers rows l*32..l*32+31. Thread's row-in-line:
    const int lr  = w*8 + (lane >> 3);                    // 0..31
    const int lcb = ((lane & 7) ^ (lane >> 3)) * 8;       // pre-swizzled col (elems)
    const bf16* aln[4];
    const bf16* bln[4];
    #pragma unroll
    for (int l = 0; l < 4; ++l) {
        const int r    = l*32 + lr;                       // 0..127
        const int grow = R0 + r;
        const bf16* a;
        if (MODE == 2) {
            a = Abf + (size_t)grow*DIM;
        } else if (MODE == 1) {
            const int t = grow & (S_LEN - 1);
            if      (t == 0) a = A1  + (size_t)(grow >> 9)*DIM;
            else if (t == 1) a = V0b + (size_t)(grow >> 9)*DIM;
            else             a = Abf + (size_t)(grow - 1)*DIM;
        } else {
            const int t = grow & (S_LEN - 1);
            a = (t >= shift) ? (Abf + (size_t)(grow - shift)*DIM) : Zr;
        }
        aln[l] = a + lcb;
        bln[l] = Bt + (size_t)(C0 + r)*DIM + lcb;
    }

    // prologue: stage tile 0 into buf 0, order A0,A2,B0,B2,A1,A3,B1,B3
    {
        unsigned short* Ad = &As[0][0];
        unsigned short* Bd = &Bs[0][0];
        gld16(aln[0], Ad + 0*2048 + w*512);
        gld16(aln[2], Ad + 2*2048 + w*512);
        gld16(bln[0], Bd + 0*2048 + w*512);
        gld16(bln[2], Bd + 2*2048 + w*512);
        gld16(aln[1], Ad + 1*2048 + w*512);
        gld16(aln[3], Ad + 3*2048 + w*512);
        gld16(bln[1], Bd + 1*2048 + w*512);
        gld16(bln[3], Bd + 3*2048 + w*512);
    }
    asm volatile("s_waitcnt vmcnt(4)" ::: "memory");
    __builtin_amdgcn_s_barrier();

#define PHASE(MQ, NQ, STAGEA, L0, L1, DOWAIT)                                   \
    {                                                                           \
        short8 af0 = lds_frag(&As[cur][0], wm + (MQ)*32 +  0 + cn,      quad*8);\
        short8 af1 = lds_frag(&As[cur][0], wm + (MQ)*32 + 16 + cn,      quad*8);\
        short8 af2 = lds_frag(&As[cur][0], wm + (MQ)*32 +  0 + cn, 32 + quad*8);\
        short8 af3 = lds_frag(&As[cur][0], wm + (MQ)*32 + 16 + cn, 32 + quad*8);\
        short8 bg0 = lds_frag(&Bs[cur][0], wn + (NQ)*32 +  0 + cn,      quad*8);\
        short8 bg1 = lds_frag(&Bs[cur][0], wn + (NQ)*32 + 16 + cn,      quad*8);\
        short8 bg2 = lds_frag(&Bs[cur][0], wn + (NQ)*32 +  0 + cn, 32 + quad*8);\
        short8 bg3 = lds_frag(&Bs[cur][0], wn + (NQ)*32 + 16 + cn, 32 + quad*8);\
        if (STAGEA) {                                                           \
            gld16(aln[L0] + knt, Ad + (L0)*2048 + w*512);                       \
            gld16(aln[L1] + knt, Ad + (L1)*2048 + w*512);                       \
        } else {                                                                \
            gld16(bln[L0] + knt, Bd + (L0)*2048 + w*512);                       \
            gld16(bln[L1] + knt, Bd + (L1)*2048 + w*512);                       \
        }                                                                       \
        __builtin_amdgcn_s_barrier();                                           \
        __builtin_amdgcn_s_setprio(1);                                          \
        acc[(MQ)*2+0][(NQ)*2+0] = __builtin_amdgcn_mfma_f32_16x16x32_bf16(af0, bg0, acc[(MQ)*2+0][(NQ)*2+0], 0, 0, 0); \
        acc[(MQ)*2+1][(NQ)*2+0] = __builtin_amdgcn_mfma_f32_16x16x32_bf16(af1, bg0, acc[(MQ)*2+1][(NQ)*2+0], 0, 0, 0); \
        acc[(MQ)*2+0][(NQ)*2+1] = __builtin_amdgcn_mfma_f32_16x16x32_bf16(af0, bg1, acc[(MQ)*2+0][(NQ)*2+1], 0, 0, 0); \
        acc[(MQ)*2+1][(NQ)*2+1] = __builtin_amdgcn_mfma_f32_16x16x32_bf16(af1, bg1, acc[(MQ)*2+1][(NQ)*2+1], 0, 0, 0); \
        acc[(MQ)*2+0][(NQ)*2+0] = __builtin_amdgcn_mfma_f32_16x16x32_bf16(af2, bg2, acc[(MQ)*2+0][(NQ)*2+0], 0, 0, 0); \
        acc[(MQ)*2+1][(NQ)*2+0] = __builtin_amdgcn_mfma_f32_16x16x32_bf16(af3, bg2, acc[(MQ)*2+1][(NQ)*2+0], 0, 0, 0); \
        acc[(MQ)*2+0][(NQ)*2+1] = __builtin_amdgcn_mfma_f32_16x16x32_bf16(af2, bg3, acc[(MQ)*2+0][(NQ)*2+1], 0, 0, 0); \
        acc[(MQ)*2+1][(NQ)*2+1] = __builtin_amdgcn_mfma_f32_16x16x32_bf16(af3, bg3, acc[(MQ)*2+1][(NQ)*2+1], 0, 0, 0); \
        __builtin_amdgcn_s_setprio(0);                                          \
        if (DOWAIT) asm volatile("s_waitcnt vmcnt(4)" ::: "memory");            \
        __builtin_amdgcn_s_barrier();                                           \
    }

    #pragma unroll
    for (int kt = 0; kt < 8; ++kt) {
        const int cur = kt & 1;
        const int knt = ((kt + 1) & 7) * 64;   // kt=7 stages a dummy (tile-0 data) into the released buf
        unsigned short* Ad = &As[cur ^ 1][0];
        unsigned short* Bd = &Bs[cur ^ 1][0];
        PHASE(0, 0, true,  0, 2, 1)
        PHASE(1, 0, false, 0, 2, 1)
        PHASE(0, 1, true,  1, 3, 0)
        PHASE(1, 1, false, 1, 3, 1)
    }
#undef PHASE
    asm volatile("s_waitcnt vmcnt(0)" ::: "memory");

    const int f32o = TO_OUT ? *flagp : 0;
    #pragma unroll
    for (int i = 0; i < 4; ++i) {
        const int rowb = R0 + wm + i*16 + quad*4;
        #pragma unroll
        for (int j = 0; j < 4; ++j) {
            const int cc = C0 + wn + j*16 + cn;
            #pragma unroll
            for (int rr = 0; rr < 4; ++rr) {
                const size_t off = (size_t)(rowb + rr)*DIM + cc;
                const float res = (MODE == 2) ? Rf[cc] : Rf[off];
                const float v = acc[i][j][rr] + res;
                if (TO_OUT) {
                    if (f32o) ((float*)Oout)[eoff + off] = v;
                    else      ((bf16*)Oout)[eoff + off]  = __float2bfloat16(v);
                } else {
                    Of[off] = v;
                    Ob[off] = __float2bfloat16(v);
                }
            }
        }
    }
}

// final_state[b,:] = outputs[b, len_b - 1, :]
__global__ void gather_final(void* __restrict__ out, const int* __restrict__ lens,
                             const int* __restrict__ flagp)
{
    const int f32 = *flagp;
    const int idx = blockIdx.x * 256 + threadIdx.x;
    const int b = idx >> 9, n = idx & 511;
    int L = lens[b];
    if (L < 1) L = 1;
    if (L > S_LEN) L = S_LEN;
    const size_t src = ((size_t)b*S_LEN + (L - 1))*DIM + n;
    const size_t dst = (size_t)ROWS*DIM + idx;
    if (f32) ((float*)out)[dst] = ((const float*)out)[src];
    else     ((bf16*)out)[dst]  = ((const bf16*)out)[src];
}

// ---------------------------------------------------------------------------
extern "C" void kernel_launch(void* const* d_in, const int* in_sizes, int n_in,
                              void* d_out, int out_size, void* d_ws, size_t ws_size,
                              hipStream_t stream)
{
    const void* X  = d_in[0];
    const void* Wi = d_in[1];
    const void* bi = d_in[2];
    // d_in[3..6] = Wq, bq, Wk, bk — dead (softmax over singleton axis == 1)
    const void* Wv = d_in[7];
    const void* bv = d_in[8];
    const void* Wo = d_in[9];
    const void* bo = d_in[10];
    const int* lens = (const int*)d_in[11];
    char* ws = (char*)d_ws;

    // ---- fixed workspace layout ----
    const size_t MATB = (size_t)DIM * DIM * sizeof(bf16);    // 524288
    bf16* WiT = (bf16*)(ws + 0*MATB);
    bf16* WoT = (bf16*)(ws + 1*MATB);
    bf16* Wvb = (bf16*)(ws + 2*MATB);
    bf16* S2  = (bf16*)(ws + 3*MATB);   // W, then W^4
    bf16* S3  = (bf16*)(ws + 4*MATB);   // W^2, then W^8
    bf16* T0  = (bf16*)(ws + 5*MATB);   // W^T
    bf16* T1  = (bf16*)(ws + 6*MATB);   // (W^2)^T
    bf16* T2  = (bf16*)(ws + 7*MATB);   // (W^4)^T
    bf16* T3  = (bf16*)(ws + 8*MATB);   // (W^8)^T
    size_t off = 9*MATB;
    float* dvec = (float*)(ws + off); off += 2048;
    float* bvec = (float*)(ws + off); off += 2048;
    int*   flag = (int*)  (ws + off); off += 256;
    float* U0   = (float*)(ws + off); off += (size_t)BATCH*DIM*4;  // 262144
    float* V0   = (float*)(ws + off); off += (size_t)BATCH*DIM*4;
    bf16*  A1   = (bf16*) (ws + off); off += (size_t)BATCH*DIM*2;  // 131072
    bf16*  V0b  = (bf16*) (ws + off); off += (size_t)BATCH*DIM*2;
    bf16*  Zr   = (bf16*) (ws + off); off += 1024;
    off = (off + 1023) & ~(size_t)1023;
    char* dyn = ws + off;
    const size_t avail = ws_size > off ? ws_size - off : 0;

    // per-chunk: xbf (CR*1024) + Uf (CR*2048) + Ub (CR*1024) + Vf (CR*2048) + Vb (CR*1024)
    int CR = 512;
    for (long cr = 65536; cr >= 512; cr >>= 1)
        if ((size_t)cr * 7168 <= avail) { CR = (int)cr; break; }

    bf16*  xbf = (bf16*) dyn;
    float* Uf  = (float*)(dyn + (size_t)CR*1024);
    bf16*  Ub  = (bf16*) (dyn + (size_t)CR*3072);
    float* Vf  = (float*)(dyn + (size_t)CR*4096);
    bf16*  Vb  = (bf16*) (dyn + (size_t)CR*6144);

    detect_dtype<<<1, 256, 0, stream>>>((const unsigned int*)X, flag);
    conv_tr<<<dim3(16,16), dim3(32,8), 0, stream>>>(Wi, WiT, flag);
    conv_tr<<<dim3(16,16), dim3(32,8), 0, stream>>>(Wo, WoT, flag);
    conv_cp<<<1024, 256, 0, stream>>>(Wv, Wvb, flag);
    cvec_kernel<<<128, 256, 0, stream>>>(WoT, bv, bo, bi, flag, dvec, bvec);
    gemm_sq<<<dim3(4,4), 256, 0, stream>>>(Wvb, WoT, S2, T0);   // W
    gemm_sq<<<dim3(4,4), 256, 0, stream>>>(S2, T0, S3, T1);     // W^2
    gemm_sq<<<dim3(4,4), 256, 0, stream>>>(S3, T1, S2, T2);     // W^4
    gemm_sq<<<dim3(4,4), 256, 0, stream>>>(S2, T2, S3, T3);     // W^8
    gemm_row0<<<dim3(4,1), 256, 0, stream>>>(X, WiT, bvec, flag, U0);
    gemm_v0<<<dim3(4,1), 256, 0, stream>>>(U0, T0, dvec, V0);
    prep_aux<<<256, 256, 0, stream>>>(U0, V0, dvec, A1, V0b, Zr);

    const int NC = ROWS / CR;
    const int RT = CR / 128;
    const int nb = 4 * RT;
    for (int c = 0; c < NC; ++c) {
        const size_t eoff = (size_t)c*CR*DIM;
        const size_t boff = (size_t)(c*(CR/S_LEN))*DIM;
        conv_x<<<CR/4, 256, 0, stream>>>(X, eoff, xbf, flag);
        gemm_big<2,false><<<nb, 256, 0, stream>>>(xbf, nullptr, nullptr, Zr,
                WiT, bvec, Uf, Ub, nullptr, 0, flag, 0);
        gemm_big<1,false><<<nb, 256, 0, stream>>>(Ub, A1 + boff, V0b + boff, Zr,
                T0, Uf, Vf, Vb, nullptr, 0, flag, 1);
        gemm_big<0,false><<<nb, 256, 0, stream>>>(Vb, nullptr, nullptr, Zr,
                T1, Vf, Uf, Ub, nullptr, 0, flag, 2);
        gemm_big<0,false><<<nb, 256, 0, stream>>>(Ub, nullptr, nullptr, Zr,
                T2, Uf, Vf, Vb, nullptr, 0, flag, 4);
        gemm_big<0,true ><<<nb, 256, 0, stream>>>(Vb, nullptr, nullptr, Zr,
                T3, Vf, nullptr, nullptr, d_out, eoff, flag, 8);
    }
    gather_final<<<256, 256, 0, stream>>>(d_out, lens, flag);
}

// Round 4
// 993.783 us; speedup vs baseline: 1.0771x; 1.0224x over previous
//
#include <hip/hip_runtime.h>
#include <hip/hip_bf16.h>

typedef __hip_bfloat16 bf16;
typedef __attribute__((ext_vector_type(8))) short short8;
typedef __attribute__((ext_vector_type(4))) float f32x4;

#define S_LEN 512
#define DIM   512
#define BATCH 128
#define ROWS  (BATCH * S_LEN)

__device__ inline unsigned short f2bu(float f){
    bf16 h = __float2bfloat16(f);
    return *reinterpret_cast<unsigned short*>(&h);
}
__device__ inline float ld_in(const void* p, size_t i, int f32){
    return f32 ? ((const float*)p)[i] : __bfloat162float(((const bf16*)p)[i]);
}

// async global->LDS, 16B per lane; LDS dest = wave-uniform base + lane*16
typedef __attribute__((address_space(1))) const unsigned int gu32;
typedef __attribute__((address_space(3))) unsigned int lu32;
__device__ __forceinline__ void gld16(const void* g, void* l){
    __builtin_amdgcn_global_load_lds((gu32*)g, (lu32*)l, 16, 0, 0);
}

// swizzled LDS fragment read: byte = (row*128 + koff*2) ^ ((row&7)<<4)
// (matches the pre-swizzled global source column permutation at stage time)
__device__ __forceinline__ short8 lds_frag(const unsigned short* base, int row, int koff){
    const unsigned off = ((unsigned)(row*128 + koff*2)) ^ (((unsigned)(row & 7)) << 4);
    return *(const short8*)((const char*)base + off);
}

// ---------------------------------------------------------------------------
// dtype detector (unchanged)
// ---------------------------------------------------------------------------
__global__ void detect_dtype(const unsigned int* __restrict__ x, int* __restrict__ flag)
{
    __shared__ int cnt;
    if (threadIdx.x == 0) cnt = 0;
    __syncthreads();
    int loc = 0;
    for (int i = threadIdx.x; i < 8192; i += 256)
        if (((x[i] >> 7) & 0xFFu) == 0xFFu) loc++;
    atomicAdd(&cnt, loc);
    __syncthreads();
    if (threadIdx.x == 0) *flag = (cnt > 0) ? 1 : 0;
}

// ---------------------------------------------------------------------------
// converters (unchanged)
// ---------------------------------------------------------------------------
__global__ void conv_tr(const void* __restrict__ in, bf16* __restrict__ outp,
                        const int* __restrict__ flagp)
{
    const int f32 = *flagp;
    __shared__ unsigned short tile[32][33];
    const int bx = blockIdx.x, by = blockIdx.y;
    const int tx = threadIdx.x, ty = threadIdx.y;   // 32 x 8
    #pragma unroll
    for (int j = 0; j < 32; j += 8)
        tile[ty + j][tx] = f2bu(ld_in(in, (size_t)(by*32 + ty + j)*DIM + bx*32 + tx, f32));
    __syncthreads();
    #pragma unroll
    for (int j = 0; j < 32; j += 8) {
        unsigned short u = tile[tx][ty + j];
        outp[(size_t)(bx*32 + ty + j)*DIM + by*32 + tx] = *reinterpret_cast<bf16*>(&u);
    }
}

__global__ void conv_cp(const void* __restrict__ in, bf16* __restrict__ outp,
                        const int* __restrict__ flagp)
{
    const int f32 = *flagp;
    const size_t i = (size_t)blockIdx.x*256 + threadIdx.x;
    outp[i] = __float2bfloat16(ld_in(in, i, f32));
}

// x (any dtype) -> bf16, 8 elems/thread, chunk at element offset eoff
__global__ void conv_x(const void* __restrict__ X, size_t eoff, bf16* __restrict__ xb,
                       const int* __restrict__ flagp)
{
    const int f32 = *flagp;
    const size_t i = ((size_t)blockIdx.x*256 + threadIdx.x)*8;
    if (f32) {
        const float* p = (const float*)X + eoff + i;
        float4 a = *(const float4*)p;
        float4 b = *(const float4*)(p + 4);
        __align__(16) unsigned short wv[8];
        wv[0]=f2bu(a.x); wv[1]=f2bu(a.y); wv[2]=f2bu(a.z); wv[3]=f2bu(a.w);
        wv[4]=f2bu(b.x); wv[5]=f2bu(b.y); wv[6]=f2bu(b.z); wv[7]=f2bu(b.w);
        *(uint4*)(xb + i) = *(const uint4*)wv;
    } else {
        *(uint4*)(xb + i) = *(const uint4*)((const bf16*)X + eoff + i);
    }
}

// ---------------------------------------------------------------------------
// dvec[n] = sum_k bv[k]*WoT[n][k] + bo[n]; bvec[n] = dvec[n] + bi[n]
// ---------------------------------------------------------------------------
__global__ void cvec_kernel(const bf16* __restrict__ WoT, const void* __restrict__ bv,
                            const void* __restrict__ bo, const void* __restrict__ bi,
                            const int* __restrict__ flagp,
                            float* __restrict__ dvec, float* __restrict__ bvec)
{
    const int f32 = *flagp;
    const int n = blockIdx.x * 4 + (threadIdx.x >> 6);
    const int lane = threadIdx.x & 63;
    float acc = 0.f;
    for (int k = lane; k < DIM; k += 64)
        acc += ld_in(bv, k, f32) * __bfloat162float(WoT[(size_t)n*DIM + k]);
    #pragma unroll
    for (int o = 32; o > 0; o >>= 1) acc += __shfl_down(acc, o, 64);
    if (lane == 0) {
        const float dd = acc + ld_in(bo, n, f32);
        dvec[n] = dd;
        bvec[n] = dd + ld_in(bi, n, f32);
    }
}

// special A rows for the big passes: A1[b]=bf16(U0[b]-d), V0b=bf16(V0), Zr=0
__global__ void prep_aux(const float* __restrict__ U0, const float* __restrict__ V0,
                         const float* __restrict__ dvec,
                         bf16* __restrict__ A1, bf16* __restrict__ V0b, bf16* __restrict__ Zr)
{
    const int idx = blockIdx.x * 256 + threadIdx.x;     // 65536
    const int n = idx & 511;
    A1[idx]  = __float2bfloat16(U0[idx] - dvec[n]);
    V0b[idx] = __float2bfloat16(V0[idx]);
    if (idx < 512) Zr[idx] = __float2bfloat16(0.f);
}

// ---------------------------------------------------------------------------
// Old padded-LDS tile core (kept for the small setup GEMMs)
// ---------------------------------------------------------------------------
#define TILE_PROLOGUE                                                          \
    __shared__ __align__(16) unsigned short As[128][72];                       \
    __shared__ __align__(16) unsigned short Bs[128][72];                       \
    const int tid  = threadIdx.x;                                              \
    const int lane = tid & 63;                                                 \
    const int wave = tid >> 6;                                                 \
    const int wm = (wave & 1) * 64;                                            \
    const int wn = (wave >> 1) * 64;                                           \
    const int cn = lane & 15;                                                  \
    const int quad = lane >> 4;                                                \
    f32x4 acc[4][4];                                                           \
    _Pragma("unroll")                                                          \
    for (int i = 0; i < 4; ++i)                                                \
        _Pragma("unroll")                                                      \
        for (int j = 0; j < 4; ++j) acc[i][j] = (f32x4){0.f,0.f,0.f,0.f};

#define TILE_MFMA                                                              \
        __syncthreads();                                                       \
        _Pragma("unroll")                                                      \
        for (int ks = 0; ks < 64; ks += 32) {                                  \
            short8 af[4], bfr[4];                                              \
            const int koff = ks + quad*8;                                      \
            _Pragma("unroll")                                                  \
            for (int i = 0; i < 4; ++i) af[i]  = *(const short8*)&As[wm + i*16 + cn][koff]; \
            _Pragma("unroll")                                                  \
            for (int j = 0; j < 4; ++j) bfr[j] = *(const short8*)&Bs[wn + j*16 + cn][koff]; \
            _Pragma("unroll")                                                  \
            for (int i = 0; i < 4; ++i)                                        \
                _Pragma("unroll")                                              \
                for (int j = 0; j < 4; ++j)                                    \
                    acc[i][j] = __builtin_amdgcn_mfma_f32_16x16x32_bf16(af[i], bfr[j], acc[i][j], 0, 0, 0); \
        }                                                                      \
        __syncthreads();

#define STAGE_B(Bt, C0)                                                        \
        {                                                                      \
            int r = tid >> 3; const int c = (tid & 7) * 8;                     \
            _Pragma("unroll")                                                  \
            for (int p = 0; p < 4; ++p, r += 32) {                             \
                uint4 v = *(const uint4*)((Bt) + (size_t)((C0) + r)*DIM + k0 + c); \
                *(uint4*)&Bs[r][c] = v;                                        \
            }                                                                  \
        }

#define STAGE_A_IN(SRC, BASE)                                                  \
                if (f32) {                                                     \
                    const float* sp = (const float*)(SRC) + (BASE);            \
                    float4 a = *(const float4*)sp;                             \
                    float4 b = *(const float4*)(sp + 4);                       \
                    __align__(16) unsigned short w[8];                         \
                    w[0]=f2bu(a.x); w[1]=f2bu(a.y); w[2]=f2bu(a.z); w[3]=f2bu(a.w); \
                    w[4]=f2bu(b.x); w[5]=f2bu(b.y); w[6]=f2bu(b.z); w[7]=f2bu(b.w); \
                    *(uint4*)&As[r][c] = *(const uint4*)w;                     \
                } else {                                                       \
                    *(uint4*)&As[r][c] = *(const uint4*)((const bf16*)(SRC) + (BASE)); \
                }

// ---------------------------------------------------------------------------
// gemm_sq / gemm_row0 / gemm_v0 (unchanged small setup GEMMs)
// ---------------------------------------------------------------------------
__global__ __launch_bounds__(256) void gemm_sq(const bf16* __restrict__ A,
        const bf16* __restrict__ Btm, bf16* __restrict__ Pout, bf16* __restrict__ Tout)
{
    TILE_PROLOGUE
    const int R0 = blockIdx.y * 128;
    const int C0 = blockIdx.x * 128;
    for (int k0 = 0; k0 < DIM; k0 += 64) {
        {
            int r = tid >> 3; const int c = (tid & 7) * 8;
            #pragma unroll
            for (int p = 0; p < 4; ++p, r += 32)
                *(uint4*)&As[r][c] = *(const uint4*)(A + (size_t)(R0 + r)*DIM + k0 + c);
        }
        STAGE_B(Btm, C0)
        TILE_MFMA
    }
    #pragma unroll
    for (int i = 0; i < 4; ++i) {
        const int rowb = R0 + wm + i*16 + quad*4;
        #pragma unroll
        for (int j = 0; j < 4; ++j) {
            const int cc = C0 + wn + j*16 + cn;
            #pragma unroll
            for (int rr = 0; rr < 4; ++rr) {
                const float v = acc[i][j][rr];
                Pout[(size_t)(rowb + rr)*DIM + cc] = __float2bfloat16(v);
                Tout[(size_t)cc*DIM + rowb + rr]  = __float2bfloat16(v);
            }
        }
    }
}

__global__ __launch_bounds__(256) void gemm_row0(const void* __restrict__ X,
        const bf16* __restrict__ WiT, const float* __restrict__ bvec,
        const int* __restrict__ flagp, float* __restrict__ U0)
{
    const int f32 = *flagp;
    TILE_PROLOGUE
    const int C0 = blockIdx.x * 128;
    for (int k0 = 0; k0 < DIM; k0 += 64) {
        {
            int r = tid >> 3; const int c = (tid & 7) * 8;
            #pragma unroll
            for (int p = 0; p < 4; ++p, r += 32) {
                const size_t base = (size_t)r*S_LEN*DIM + k0 + c;
                STAGE_A_IN(X, base)
            }
        }
        STAGE_B(WiT, C0)
        TILE_MFMA
    }
    #pragma unroll
    for (int i = 0; i < 4; ++i) {
        const int rowb = wm + i*16 + quad*4;
        #pragma unroll
        for (int j = 0; j < 4; ++j) {
            const int cc = C0 + wn + j*16 + cn;
            const float bb = bvec[cc];
            #pragma unroll
            for (int rr = 0; rr < 4; ++rr)
                U0[(size_t)(rowb + rr)*DIM + cc] = acc[i][j][rr] + bb;
        }
    }
}

__global__ __launch_bounds__(256) void gemm_v0(const float* __restrict__ U0,
        const bf16* __restrict__ T0, const float* __restrict__ dvec, float* __restrict__ V0)
{
    TILE_PROLOGUE
    const int C0 = blockIdx.x * 128;
    for (int k0 = 0; k0 < DIM; k0 += 64) {
        {
            int r = tid >> 3; const int c = (tid & 7) * 8;
            #pragma unroll
            for (int p = 0; p < 4; ++p, r += 32) {
                __align__(16) unsigned short w[8];
                #pragma unroll
                for (int q = 0; q < 8; ++q)
                    w[q] = f2bu(U0[(size_t)r*DIM + k0 + c + q] - dvec[k0 + c + q]);
                *(uint4*)&As[r][c] = *(const uint4*)w;
            }
        }
        STAGE_B(T0, C0)
        TILE_MFMA
    }
    #pragma unroll
    for (int i = 0; i < 4; ++i) {
        const int rowb = wm + i*16 + quad*4;
        #pragma unroll
        for (int j = 0; j < 4; ++j) {
            const int cc = C0 + wn + j*16 + cn;
            #pragma unroll
            for (int rr = 0; rr < 4; ++rr) {
                const size_t off = (size_t)(rowb + rr)*DIM + cc;
                V0[off] = acc[i][j][rr] + U0[off];
            }
        }
    }
}

// ---------------------------------------------------------------------------
// gemm_big (round-3 structure, kept for MODE 2 / MODE 1 / TO_OUT passes)
// ---------------------------------------------------------------------------
template<int MODE, bool TO_OUT>
__global__ __launch_bounds__(256, 2) void gemm_big(
        const bf16* __restrict__ Abf, const bf16* __restrict__ A1,
        const bf16* __restrict__ V0b, const bf16* __restrict__ Zr,
        const bf16* __restrict__ Bt,  const float* __restrict__ Rf,
        float* __restrict__ Of, bf16* __restrict__ Ob,
        void* __restrict__ Oout, size_t eoff, const int* __restrict__ flagp,
        const int shift)
{
    __shared__ __align__(16) unsigned short As[2][128*64];
    __shared__ __align__(16) unsigned short Bs[2][128*64];
    const int tid  = threadIdx.x;
    const int lane = tid & 63;
    const int w    = tid >> 6;
    const int nb = gridDim.x;
    const int p0 = blockIdx.x;
    const int L  = (p0 & 7) * (nb >> 3) + (p0 >> 3);
    const int bx = L & 3, by = L >> 2;
    const int R0 = by * 128, C0 = bx * 128;
    const int wm = (w & 1) * 64;
    const int wn = (w >> 1) * 64;
    const int cn = lane & 15;
    const int quad = lane >> 4;
    f32x4 acc[4][4];
    #pragma unroll
    for (int i = 0; i < 4; ++i)
        #pragma unroll
        for (int j = 0; j < 4; ++j) acc[i][j] = (f32x4){0.f,0.f,0.f,0.f};

    const int lr  = w*8 + (lane >> 3);
    const int lcb = ((lane & 7) ^ (lane >> 3)) * 8;
    const bf16* aln[4];
    const bf16* bln[4];
    #pragma unroll
    for (int l = 0; l < 4; ++l) {
        const int r    = l*32 + lr;
        const int grow = R0 + r;
        const bf16* a;
        if (MODE == 2) {
            a = Abf + (size_t)grow*DIM;
        } else if (MODE == 1) {
            const int t = grow & (S_LEN - 1);
            if      (t == 0) a = A1  + (size_t)(grow >> 9)*DIM;
            else if (t == 1) a = V0b + (size_t)(grow >> 9)*DIM;
            else             a = Abf + (size_t)(grow - 1)*DIM;
        } else {
            const int t = grow & (S_LEN - 1);
            a = (t >= shift) ? (Abf + (size_t)(grow - shift)*DIM) : Zr;
        }
        aln[l] = a + lcb;
        bln[l] = Bt + (size_t)(C0 + r)*DIM + lcb;
    }

    {
        unsigned short* Ad = &As[0][0];
        unsigned short* Bd = &Bs[0][0];
        gld16(aln[0], Ad + 0*2048 + w*512);
        gld16(aln[2], Ad + 2*2048 + w*512);
        gld16(bln[0], Bd + 0*2048 + w*512);
        gld16(bln[2], Bd + 2*2048 + w*512);
        gld16(aln[1], Ad + 1*2048 + w*512);
        gld16(aln[3], Ad + 3*2048 + w*512);
        gld16(bln[1], Bd + 1*2048 + w*512);
        gld16(bln[3], Bd + 3*2048 + w*512);
    }
    asm volatile("s_waitcnt vmcnt(4)" ::: "memory");
    __builtin_amdgcn_s_barrier();

#define PHASE(MQ, NQ, STAGEA, L0, L1, DOWAIT)                                   \
    {                                                                           \
        short8 af0 = lds_frag(&As[cur][0], wm + (MQ)*32 +  0 + cn,      quad*8);\
        short8 af1 = lds_frag(&As[cur][0], wm + (MQ)*32 + 16 + cn,      quad*8);\
        short8 af2 = lds_frag(&As[cur][0], wm + (MQ)*32 +  0 + cn, 32 + quad*8);\
        short8 af3 = lds_frag(&As[cur][0], wm + (MQ)*32 + 16 + cn, 32 + quad*8);\
        short8 bg0 = lds_frag(&Bs[cur][0], wn + (NQ)*32 +  0 + cn,      quad*8);\
        short8 bg1 = lds_frag(&Bs[cur][0], wn + (NQ)*32 + 16 + cn,      quad*8);\
        short8 bg2 = lds_frag(&Bs[cur][0], wn + (NQ)*32 +  0 + cn, 32 + quad*8);\
        short8 bg3 = lds_frag(&Bs[cur][0], wn + (NQ)*32 + 16 + cn, 32 + quad*8);\
        if (STAGEA) {                                                           \
            gld16(aln[L0] + knt, Ad + (L0)*2048 + w*512);                       \
            gld16(aln[L1] + knt, Ad + (L1)*2048 + w*512);                       \
        } else {                                                                \
            gld16(bln[L0] + knt, Bd + (L0)*2048 + w*512);                       \
            gld16(bln[L1] + knt, Bd + (L1)*2048 + w*512);                       \
        }                                                                       \
        __builtin_amdgcn_s_barrier();                                           \
        __builtin_amdgcn_s_setprio(1);                                          \
        acc[(MQ)*2+0][(NQ)*2+0] = __builtin_amdgcn_mfma_f32_16x16x32_bf16(af0, bg0, acc[(MQ)*2+0][(NQ)*2+0], 0, 0, 0); \
        acc[(MQ)*2+1][(NQ)*2+0] = __builtin_amdgcn_mfma_f32_16x16x32_bf16(af1, bg0, acc[(MQ)*2+1][(NQ)*2+0], 0, 0, 0); \
        acc[(MQ)*2+0][(NQ)*2+1] = __builtin_amdgcn_mfma_f32_16x16x32_bf16(af0, bg1, acc[(MQ)*2+0][(NQ)*2+1], 0, 0, 0); \
        acc[(MQ)*2+1][(NQ)*2+1] = __builtin_amdgcn_mfma_f32_16x16x32_bf16(af1, bg1, acc[(MQ)*2+1][(NQ)*2+1], 0, 0, 0); \
        acc[(MQ)*2+0][(NQ)*2+0] = __builtin_amdgcn_mfma_f32_16x16x32_bf16(af2, bg2, acc[(MQ)*2+0][(NQ)*2+0], 0, 0, 0); \
        acc[(MQ)*2+1][(NQ)*2+0] = __builtin_amdgcn_mfma_f32_16x16x32_bf16(af3, bg2, acc[(MQ)*2+1][(NQ)*2+0], 0, 0, 0); \
        acc[(MQ)*2+0][(NQ)*2+1] = __builtin_amdgcn_mfma_f32_16x16x32_bf16(af2, bg3, acc[(MQ)*2+0][(NQ)*2+1], 0, 0, 0); \
        acc[(MQ)*2+1][(NQ)*2+1] = __builtin_amdgcn_mfma_f32_16x16x32_bf16(af3, bg3, acc[(MQ)*2+1][(NQ)*2+1], 0, 0, 0); \
        __builtin_amdgcn_s_setprio(0);                                          \
        if (DOWAIT) asm volatile("s_waitcnt vmcnt(4)" ::: "memory");            \
        __builtin_amdgcn_s_barrier();                                           \
    }

    #pragma unroll
    for (int kt = 0; kt < 8; ++kt) {
        const int cur = kt & 1;
        const int knt = ((kt + 1) & 7) * 64;
        unsigned short* Ad = &As[cur ^ 1][0];
        unsigned short* Bd = &Bs[cur ^ 1][0];
        PHASE(0, 0, true,  0, 2, 1)
        PHASE(1, 0, false, 0, 2, 1)
        PHASE(0, 1, true,  1, 3, 0)
        PHASE(1, 1, false, 1, 3, 1)
    }
#undef PHASE
    asm volatile("s_waitcnt vmcnt(0)" ::: "memory");

    const int f32o = TO_OUT ? *flagp : 0;
    #pragma unroll
    for (int i = 0; i < 4; ++i) {
        const int rowb = R0 + wm + i*16 + quad*4;
        #pragma unroll
        for (int j = 0; j < 4; ++j) {
            const int cc = C0 + wn + j*16 + cn;
            #pragma unroll
            for (int rr = 0; rr < 4; ++rr) {
                const size_t off = (size_t)(rowb + rr)*DIM + cc;
                const float res = (MODE == 2) ? Rf[cc] : Rf[off];
                const float v = acc[i][j][rr] + res;
                if (TO_OUT) {
                    if (f32o) ((float*)Oout)[eoff + off] = v;
                    else      ((bf16*)Oout)[eoff + off]  = __float2bfloat16(v);
                } else {
                    Of[off] = v;
                    Ob[off] = __float2bfloat16(v);
                }
            }
        }
    }
}

// ---------------------------------------------------------------------------
// gemm_256: m201-geometry MODE-0 pass. 256x256 tile, 512 threads (8 waves,
// 2M x 4N, 128x64 per wave), BK=64, 128 KiB dbuf LDS (dynamic), 4 phases per
// K-tile, counted vmcnt (never 0 in main loop), setprio around MFMA clusters.
// Stage lines (8KB = 64 rows x 64 k): order per tile: p0:{B0,B1} p1:{B2,B3}
// p2:{A0,A2} p3:{A1,A3}. Waits: vmcnt(4) after p1 (drains current tile's late
// A-lines 1,3), vmcnt(2) after p3 (boundary; leaves next tile's A1,A3 in
// flight). Same read-XOR / pre-swizzled-source involution as gemm_big.
// out = A @ Bt^T + Rf, dual-store fp32 Of + bf16 Ob. A rows shifted by
// `shift` within each sequence (t<shift -> zero row Zr).
// ---------------------------------------------------------------------------
__global__ __launch_bounds__(512, 2) void gemm_256(
        const bf16* __restrict__ Abf, const bf16* __restrict__ Zr,
        const bf16* __restrict__ Bt,  const float* __restrict__ Rf,
        float* __restrict__ Of, bf16* __restrict__ Ob, const int shift)
{
    extern __shared__ __align__(16) unsigned short smem[];
    unsigned short* Ab0 = smem;                 // 16384 ushorts = 32KB
    unsigned short* Ab1 = smem + 16384;
    unsigned short* Bb0 = smem + 32768;
    unsigned short* Bb1 = smem + 49152;

    const int tid  = threadIdx.x;
    const int lane = tid & 63;
    const int w    = tid >> 6;                  // 0..7
    const int nb = gridDim.x;
    const int p0 = blockIdx.x;
    const int L  = ((nb & 7) == 0) ? ((p0 & 7) * (nb >> 3) + (p0 >> 3)) : p0;
    const int bx = L & 1, by = L >> 1;          // N=512 -> 2 col blocks
    const int R0 = by * 256, C0 = bx * 256;
    const int wr = w >> 2, wc = w & 3;          // 2M x 4N
    const int cn = lane & 15, quad = lane >> 4;

    f32x4 acc[8][4];
    #pragma unroll
    for (int i = 0; i < 8; ++i)
        #pragma unroll
        for (int j = 0; j < 4; ++j) acc[i][j] = (f32x4){0.f,0.f,0.f,0.f};

    // staging addressing: line l = rows 64l..64l+63; this thread's row/col
    const int lrow = w*8 + (lane >> 3);                  // 0..63 within line
    const int scol = ((lane & 7) ^ (lane >> 3)) * 8;     // pre-swizzled col
    const int ldst = w * 512;                            // ushort offset in line
    const bf16* bl0 = Bt + (size_t)(C0 + lrow)*DIM + scol;   // + l*64*DIM
    const bf16* aln[4];
    #pragma unroll
    for (int l = 0; l < 4; ++l) {
        const int grow = R0 + l*64 + lrow;
        const int t = grow & (S_LEN - 1);
        const bf16* a = (t >= shift) ? (Abf + (size_t)(grow - shift)*DIM) : Zr;
        aln[l] = a + scol;
    }

    // prologue: tile 0 -> buf0; order B0 B1 B2 B3 A0 A2 A1 A3; vmcnt(2)
    gld16(bl0 + 0*64*DIM, Bb0 + 0*4096 + ldst);
    gld16(bl0 + 1*64*DIM, Bb0 + 1*4096 + ldst);
    gld16(bl0 + 2*64*DIM, Bb0 + 2*4096 + ldst);
    gld16(bl0 + 3*64*DIM, Bb0 + 3*4096 + ldst);
    gld16(aln[0], Ab0 + 0*4096 + ldst);
    gld16(aln[2], Ab0 + 2*4096 + ldst);
    gld16(aln[1], Ab0 + 1*4096 + ldst);
    gld16(aln[3], Ab0 + 3*4096 + ldst);
    asm volatile("s_waitcnt vmcnt(2)" ::: "memory");
    __builtin_amdgcn_s_barrier();

#define MFMA16(Q)                                                              \
    __builtin_amdgcn_s_setprio(1);                                             \
    _Pragma("unroll")                                                          \
    for (int n = 0; n < 4; ++n) {                                              \
        acc[(Q)*2+0][n] = __builtin_amdgcn_mfma_f32_16x16x32_bf16(x0, bg0[n], acc[(Q)*2+0][n], 0, 0, 0); \
        acc[(Q)*2+1][n] = __builtin_amdgcn_mfma_f32_16x16x32_bf16(x1, bg0[n], acc[(Q)*2+1][n], 0, 0, 0); \
    }                                                                          \
    _Pragma("unroll")                                                          \
    for (int n = 0; n < 4; ++n) {                                              \
        acc[(Q)*2+0][n] = __builtin_amdgcn_mfma_f32_16x16x32_bf16(x2, bg1[n], acc[(Q)*2+0][n], 0, 0, 0); \
        acc[(Q)*2+1][n] = __builtin_amdgcn_mfma_f32_16x16x32_bf16(x3, bg1[n], acc[(Q)*2+1][n], 0, 0, 0); \
    }                                                                          \
    __builtin_amdgcn_s_setprio(0);

#define RDA(Q, KH) \
    x0 = lds_frag(Ac, wr*128 + ((Q)*2+0)*16 + cn, (KH)*32 + quad*8);           \
    x1 = lds_frag(Ac, wr*128 + ((Q)*2+1)*16 + cn, (KH)*32 + quad*8);

#define RDA4(Q)                                                                \
    x0 = lds_frag(Ac, wr*128 + ((Q)*2+0)*16 + cn,      quad*8);                \
    x1 = lds_frag(Ac, wr*128 + ((Q)*2+1)*16 + cn,      quad*8);                \
    x2 = lds_frag(Ac, wr*128 + ((Q)*2+0)*16 + cn, 32 + quad*8);                \
    x3 = lds_frag(Ac, wr*128 + ((Q)*2+1)*16 + cn, 32 + quad*8);

    // main loop: tiles 0..6 stage tile kt+1; tile 7 peeled (no staging)
    for (int kt = 0; kt < 7; ++kt) {
        const int knt = (kt + 1) << 6;
        unsigned short* Ac = (kt & 1) ? Ab1 : Ab0;
        unsigned short* Bc = (kt & 1) ? Bb1 : Bb0;
        unsigned short* An = (kt & 1) ? Ab0 : Ab1;
        unsigned short* Bn = (kt & 1) ? Bb0 : Bb1;
        short8 bg0[4], bg1[4];
        short8 x0, x1, x2, x3;
        // p0: read B frags + A q0; stage B0,B1; MFMA q0
        #pragma unroll
        for (int n = 0; n < 4; ++n) {
            bg0[n] = lds_frag(Bc, wc*64 + n*16 + cn,      quad*8);
            bg1[n] = lds_frag(Bc, wc*64 + n*16 + cn, 32 + quad*8);
        }
        RDA4(0)
        gld16(bl0 + 0*64*DIM + knt, Bn + 0*4096 + ldst);
        gld16(bl0 + 1*64*DIM + knt, Bn + 1*4096 + ldst);
        MFMA16(0)
        // p1: A q1; stage B2,B3; MFMA q1; vmcnt(4); barrier
        RDA4(1)
        gld16(bl0 + 2*64*DIM + knt, Bn + 2*4096 + ldst);
        gld16(bl0 + 3*64*DIM + knt, Bn + 3*4096 + ldst);
        MFMA16(1)
        asm volatile("s_waitcnt vmcnt(4)" ::: "memory");
        __builtin_amdgcn_s_barrier();
        // p2: A q2; stage A0,A2; MFMA q2
        RDA4(2)
        gld16(aln[0] + knt, An + 0*4096 + ldst);
        gld16(aln[2] + knt, An + 2*4096 + ldst);
        MFMA16(2)
        // p3: A q3; stage A1,A3; MFMA q3; vmcnt(2); barrier
        RDA4(3)
        gld16(aln[1] + knt, An + 1*4096 + ldst);
        gld16(aln[3] + knt, An + 3*4096 + ldst);
        MFMA16(3)
        asm volatile("s_waitcnt vmcnt(2)" ::: "memory");
        __builtin_amdgcn_s_barrier();
    }
    // tile 7 (no staging): vmcnt(0) after p1
    {
        unsigned short* Ac = Ab1;
        unsigned short* Bc = Bb1;
        short8 bg0[4], bg1[4];
        short8 x0, x1, x2, x3;
        #pragma unroll
        for (int n = 0; n < 4; ++n) {
            bg0[n] = lds_frag(Bc, wc*64 + n*16 + cn,      quad*8);
            bg1[n] = lds_frag(Bc, wc*64 + n*16 + cn, 32 + quad*8);
        }
        RDA4(0)
        MFMA16(0)
        RDA4(1)
        MFMA16(1)
        asm volatile("s_waitcnt vmcnt(0)" ::: "memory");
        __builtin_amdgcn_s_barrier();
        RDA4(2)
        MFMA16(2)
        RDA4(3)
        MFMA16(3)
    }
#undef MFMA16
#undef RDA
#undef RDA4

    // epilogue: dual store + residual
    #pragma unroll
    for (int i = 0; i < 8; ++i) {
        const int rowb = R0 + wr*128 + i*16 + quad*4;
        #pragma unroll
        for (int j = 0; j < 4; ++j) {
            const int cc = C0 + wc*64 + j*16 + cn;
            #pragma unroll
            for (int rr = 0; rr < 4; ++rr) {
                const size_t off = (size_t)(rowb + rr)*DIM + cc;
                const float v = acc[i][j][rr] + Rf[off];
                Of[off] = v;
                Ob[off] = __float2bfloat16(v);
            }
        }
    }
}

// final_state[b,:] = outputs[b, len_b - 1, :]
__global__ void gather_final(void* __restrict__ out, const int* __restrict__ lens,
                             const int* __restrict__ flagp)
{
    const int f32 = *flagp;
    const int idx = blockIdx.x * 256 + threadIdx.x;
    const int b = idx >> 9, n = idx & 511;
    int L = lens[b];
    if (L < 1) L = 1;
    if (L > S_LEN) L = S_LEN;
    const size_t src = ((size_t)b*S_LEN + (L - 1))*DIM + n;
    const size_t dst = (size_t)ROWS*DIM + idx;
    if (f32) ((float*)out)[dst] = ((const float*)out)[src];
    else     ((bf16*)out)[dst]  = ((const bf16*)out)[src];
}

// ---------------------------------------------------------------------------
extern "C" void kernel_launch(void* const* d_in, const int* in_sizes, int n_in,
                              void* d_out, int out_size, void* d_ws, size_t ws_size,
                              hipStream_t stream)
{
    const void* X  = d_in[0];
    const void* Wi = d_in[1];
    const void* bi = d_in[2];
    // d_in[3..6] = Wq, bq, Wk, bk — dead (softmax over singleton axis == 1)
    const void* Wv = d_in[7];
    const void* bv = d_in[8];
    const void* Wo = d_in[9];
    const void* bo = d_in[10];
    const int* lens = (const int*)d_in[11];
    char* ws = (char*)d_ws;

    // ---- fixed workspace layout ----
    const size_t MATB = (size_t)DIM * DIM * sizeof(bf16);    // 524288
    bf16* WiT = (bf16*)(ws + 0*MATB);
    bf16* WoT = (bf16*)(ws + 1*MATB);
    bf16* Wvb = (bf16*)(ws + 2*MATB);
    bf16* S2  = (bf16*)(ws + 3*MATB);   // W, then W^4
    bf16* S3  = (bf16*)(ws + 4*MATB);   // W^2, then W^8
    bf16* T0  = (bf16*)(ws + 5*MATB);   // W^T
    bf16* T1  = (bf16*)(ws + 6*MATB);   // (W^2)^T
    bf16* T2  = (bf16*)(ws + 7*MATB);   // (W^4)^T
    bf16* T3  = (bf16*)(ws + 8*MATB);   // (W^8)^T
    size_t off = 9*MATB;
    float* dvec = (float*)(ws + off); off += 2048;
    float* bvec = (float*)(ws + off); off += 2048;
    int*   flag = (int*)  (ws + off); off += 256;
    float* U0   = (float*)(ws + off); off += (size_t)BATCH*DIM*4;  // 262144
    float* V0   = (float*)(ws + off); off += (size_t)BATCH*DIM*4;
    bf16*  A1   = (bf16*) (ws + off); off += (size_t)BATCH*DIM*2;  // 131072
    bf16*  V0b  = (bf16*) (ws + off); off += (size_t)BATCH*DIM*2;
    bf16*  Zr   = (bf16*) (ws + off); off += 1024;
    off = (off + 1023) & ~(size_t)1023;
    char* dyn = ws + off;
    const size_t avail = ws_size > off ? ws_size - off : 0;

    // per-chunk: xbf (CR*1024) + Uf (CR*2048) + Ub (CR*1024) + Vf (CR*2048) + Vb (CR*1024)
    int CR = 512;
    for (long cr = 65536; cr >= 512; cr >>= 1)
        if ((size_t)cr * 7168 <= avail) { CR = (int)cr; break; }

    bf16*  xbf = (bf16*) dyn;
    float* Uf  = (float*)(dyn + (size_t)CR*1024);
    bf16*  Ub  = (bf16*) (dyn + (size_t)CR*3072);
    float* Vf  = (float*)(dyn + (size_t)CR*4096);
    bf16*  Vb  = (bf16*) (dyn + (size_t)CR*6144);

    hipFuncSetAttribute(reinterpret_cast<const void*>(gemm_256),
                        hipFuncAttributeMaxDynamicSharedMemorySize, 131072);

    detect_dtype<<<1, 256, 0, stream>>>((const unsigned int*)X, flag);
    conv_tr<<<dim3(16,16), dim3(32,8), 0, stream>>>(Wi, WiT, flag);
    conv_tr<<<dim3(16,16), dim3(32,8), 0, stream>>>(Wo, WoT, flag);
    conv_cp<<<1024, 256, 0, stream>>>(Wv, Wvb, flag);
    cvec_kernel<<<128, 256, 0, stream>>>(WoT, bv, bo, bi, flag, dvec, bvec);
    gemm_sq<<<dim3(4,4), 256, 0, stream>>>(Wvb, WoT, S2, T0);   // W
    gemm_sq<<<dim3(4,4), 256, 0, stream>>>(S2, T0, S3, T1);     // W^2
    gemm_sq<<<dim3(4,4), 256, 0, stream>>>(S3, T1, S2, T2);     // W^4
    gemm_sq<<<dim3(4,4), 256, 0, stream>>>(S2, T2, S3, T3);     // W^8
    gemm_row0<<<dim3(4,1), 256, 0, stream>>>(X, WiT, bvec, flag, U0);
    gemm_v0<<<dim3(4,1), 256, 0, stream>>>(U0, T0, dvec, V0);
    prep_aux<<<256, 256, 0, stream>>>(U0, V0, dvec, A1, V0b, Zr);

    const int NC = ROWS / CR;
    const int RT = CR / 128;
    const int nb = 4 * RT;
    const int nb256 = CR / 128;     // (CR/256 row-blocks) x (512/256 col-blocks)
    for (int c = 0; c < NC; ++c) {
        const size_t eoff = (size_t)c*CR*DIM;
        const size_t boff = (size_t)(c*(CR/S_LEN))*DIM;
        conv_x<<<CR/4, 256, 0, stream>>>(X, eoff, xbf, flag);
        gemm_big<2,false><<<nb, 256, 0, stream>>>(xbf, nullptr, nullptr, Zr,
                WiT, bvec, Uf, Ub, nullptr, 0, flag, 0);
        gemm_big<1,false><<<nb, 256, 0, stream>>>(Ub, A1 + boff, V0b + boff, Zr,
                T0, Uf, Vf, Vb, nullptr, 0, flag, 1);
        gemm_256<<<nb256, 512, 131072, stream>>>(Vb, Zr, T1, Vf, Uf, Ub, 2);
        gemm_256<<<nb256, 512, 131072, stream>>>(Ub, Zr, T2, Uf, Vf, Vb, 4);
        gemm_big<0,true ><<<nb, 256, 0, stream>>>(Vb, nullptr, nullptr, Zr,
                T3, Vf, nullptr, nullptr, d_out, eoff, flag, 8);
    }
    gather_final<<<256, 256, 0, stream>>>(d_out, lens, flag);
}

// Round 5
// 963.730 us; speedup vs baseline: 1.1106x; 1.0312x over previous
//
#include <hip/hip_runtime.h>
#include <hip/hip_bf16.h>

typedef __hip_bfloat16 bf16;
typedef __attribute__((ext_vector_type(8))) short short8;
typedef __attribute__((ext_vector_type(4))) float f32x4;

#define S_LEN 512
#define DIM   512
#define BATCH 128
#define ROWS  (BATCH * S_LEN)

__device__ inline unsigned short f2bu(float f){
    bf16 h = __float2bfloat16(f);
    return *reinterpret_cast<unsigned short*>(&h);
}
__device__ inline float ld_in(const void* p, size_t i, int f32){
    return f32 ? ((const float*)p)[i] : __bfloat162float(((const bf16*)p)[i]);
}

// async global->LDS, 16B per lane; LDS dest = wave-uniform base + lane*16
typedef __attribute__((address_space(1))) const unsigned int gu32;
typedef __attribute__((address_space(3))) unsigned int lu32;
__device__ __forceinline__ void gld16(const void* g, void* l){
    __builtin_amdgcn_global_load_lds((gu32*)g, (lu32*)l, 16, 0, 0);
}

// swizzled LDS fragment read: byte = (row*128 + koff*2) ^ ((row&7)<<4)
// (matches the pre-swizzled global source column permutation at stage time)
__device__ __forceinline__ short8 lds_frag(const unsigned short* base, int row, int koff){
    const unsigned off = ((unsigned)(row*128 + koff*2)) ^ (((unsigned)(row & 7)) << 4);
    return *(const short8*)((const char*)base + off);
}

// ---------------------------------------------------------------------------
// dtype detector (unchanged)
// ---------------------------------------------------------------------------
__global__ void detect_dtype(const unsigned int* __restrict__ x, int* __restrict__ flag)
{
    __shared__ int cnt;
    if (threadIdx.x == 0) cnt = 0;
    __syncthreads();
    int loc = 0;
    for (int i = threadIdx.x; i < 8192; i += 256)
        if (((x[i] >> 7) & 0xFFu) == 0xFFu) loc++;
    atomicAdd(&cnt, loc);
    __syncthreads();
    if (threadIdx.x == 0) *flag = (cnt > 0) ? 1 : 0;
}

// ---------------------------------------------------------------------------
// converters (unchanged)
// ---------------------------------------------------------------------------
__global__ void conv_tr(const void* __restrict__ in, bf16* __restrict__ outp,
                        const int* __restrict__ flagp)
{
    const int f32 = *flagp;
    __shared__ unsigned short tile[32][33];
    const int bx = blockIdx.x, by = blockIdx.y;
    const int tx = threadIdx.x, ty = threadIdx.y;   // 32 x 8
    #pragma unroll
    for (int j = 0; j < 32; j += 8)
        tile[ty + j][tx] = f2bu(ld_in(in, (size_t)(by*32 + ty + j)*DIM + bx*32 + tx, f32));
    __syncthreads();
    #pragma unroll
    for (int j = 0; j < 32; j += 8) {
        unsigned short u = tile[tx][ty + j];
        outp[(size_t)(bx*32 + ty + j)*DIM + by*32 + tx] = *reinterpret_cast<bf16*>(&u);
    }
}

__global__ void conv_cp(const void* __restrict__ in, bf16* __restrict__ outp,
                        const int* __restrict__ flagp)
{
    const int f32 = *flagp;
    const size_t i = (size_t)blockIdx.x*256 + threadIdx.x;
    outp[i] = __float2bfloat16(ld_in(in, i, f32));
}

// x (any dtype) -> bf16, 8 elems/thread, chunk at element offset eoff
__global__ void conv_x(const void* __restrict__ X, size_t eoff, bf16* __restrict__ xb,
                       const int* __restrict__ flagp)
{
    const int f32 = *flagp;
    const size_t i = ((size_t)blockIdx.x*256 + threadIdx.x)*8;
    if (f32) {
        const float* p = (const float*)X + eoff + i;
        float4 a = *(const float4*)p;
        float4 b = *(const float4*)(p + 4);
        __align__(16) unsigned short wv[8];
        wv[0]=f2bu(a.x); wv[1]=f2bu(a.y); wv[2]=f2bu(a.z); wv[3]=f2bu(a.w);
        wv[4]=f2bu(b.x); wv[5]=f2bu(b.y); wv[6]=f2bu(b.z); wv[7]=f2bu(b.w);
        *(uint4*)(xb + i) = *(const uint4*)wv;
    } else {
        *(uint4*)(xb + i) = *(const uint4*)((const bf16*)X + eoff + i);
    }
}

// ---------------------------------------------------------------------------
// dvec[n] = sum_k bv[k]*WoT[n][k] + bo[n]; bvec[n] = dvec[n] + bi[n]
// ---------------------------------------------------------------------------
__global__ void cvec_kernel(const bf16* __restrict__ WoT, const void* __restrict__ bv,
                            const void* __restrict__ bo, const void* __restrict__ bi,
                            const int* __restrict__ flagp,
                            float* __restrict__ dvec, float* __restrict__ bvec)
{
    const int f32 = *flagp;
    const int n = blockIdx.x * 4 + (threadIdx.x >> 6);
    const int lane = threadIdx.x & 63;
    float acc = 0.f;
    for (int k = lane; k < DIM; k += 64)
        acc += ld_in(bv, k, f32) * __bfloat162float(WoT[(size_t)n*DIM + k]);
    #pragma unroll
    for (int o = 32; o > 0; o >>= 1) acc += __shfl_down(acc, o, 64);
    if (lane == 0) {
        const float dd = acc + ld_in(bo, n, f32);
        dvec[n] = dd;
        bvec[n] = dd + ld_in(bi, n, f32);
    }
}

// special A rows for the big passes: A1[b]=bf16(U0[b]-d), V0b=bf16(V0), Zr=0
__global__ void prep_aux(const float* __restrict__ U0, const float* __restrict__ V0,
                         const float* __restrict__ dvec,
                         bf16* __restrict__ A1, bf16* __restrict__ V0b, bf16* __restrict__ Zr)
{
    const int idx = blockIdx.x * 256 + threadIdx.x;     // 65536
    const int n = idx & 511;
    A1[idx]  = __float2bfloat16(U0[idx] - dvec[n]);
    V0b[idx] = __float2bfloat16(V0[idx]);
    if (idx < 512) Zr[idx] = __float2bfloat16(0.f);
}

// ---------------------------------------------------------------------------
// Old padded-LDS tile core (kept for the small setup GEMMs)
// ---------------------------------------------------------------------------
#define TILE_PROLOGUE                                                          \
    __shared__ __align__(16) unsigned short As[128][72];                       \
    __shared__ __align__(16) unsigned short Bs[128][72];                       \
    const int tid  = threadIdx.x;                                              \
    const int lane = tid & 63;                                                 \
    const int wave = tid >> 6;                                                 \
    const int wm = (wave & 1) * 64;                                            \
    const int wn = (wave >> 1) * 64;                                           \
    const int cn = lane & 15;                                                  \
    const int quad = lane >> 4;                                                \
    f32x4 acc[4][4];                                                           \
    _Pragma("unroll")                                                          \
    for (int i = 0; i < 4; ++i)                                                \
        _Pragma("unroll")                                                      \
        for (int j = 0; j < 4; ++j) acc[i][j] = (f32x4){0.f,0.f,0.f,0.f};

#define TILE_MFMA                                                              \
        __syncthreads();                                                       \
        _Pragma("unroll")                                                      \
        for (int ks = 0; ks < 64; ks += 32) {                                  \
            short8 af[4], bfr[4];                                              \
            const int koff = ks + quad*8;                                      \
            _Pragma("unroll")                                                  \
            for (int i = 0; i < 4; ++i) af[i]  = *(const short8*)&As[wm + i*16 + cn][koff]; \
            _Pragma("unroll")                                                  \
            for (int j = 0; j < 4; ++j) bfr[j] = *(const short8*)&Bs[wn + j*16 + cn][koff]; \
            _Pragma("unroll")                                                  \
            for (int i = 0; i < 4; ++i)                                        \
                _Pragma("unroll")                                              \
                for (int j = 0; j < 4; ++j)                                    \
                    acc[i][j] = __builtin_amdgcn_mfma_f32_16x16x32_bf16(af[i], bfr[j], acc[i][j], 0, 0, 0); \
        }                                                                      \
        __syncthreads();

#define STAGE_B(Bt, C0)                                                        \
        {                                                                      \
            int r = tid >> 3; const int c = (tid & 7) * 8;                     \
            _Pragma("unroll")                                                  \
            for (int p = 0; p < 4; ++p, r += 32) {                             \
                uint4 v = *(const uint4*)((Bt) + (size_t)((C0) + r)*DIM + k0 + c); \
                *(uint4*)&Bs[r][c] = v;                                        \
            }                                                                  \
        }

#define STAGE_A_IN(SRC, BASE)                                                  \
                if (f32) {                                                     \
                    const float* sp = (const float*)(SRC) + (BASE);            \
                    float4 a = *(const float4*)sp;                             \
                    float4 b = *(const float4*)(sp + 4);                       \
                    __align__(16) unsigned short w[8];                         \
                    w[0]=f2bu(a.x); w[1]=f2bu(a.y); w[2]=f2bu(a.z); w[3]=f2bu(a.w); \
                    w[4]=f2bu(b.x); w[5]=f2bu(b.y); w[6]=f2bu(b.z); w[7]=f2bu(b.w); \
                    *(uint4*)&As[r][c] = *(const uint4*)w;                     \
                } else {                                                       \
                    *(uint4*)&As[r][c] = *(const uint4*)((const bf16*)(SRC) + (BASE)); \
                }

// ---------------------------------------------------------------------------
// gemm_sq / gemm_row0 / gemm_v0 (unchanged small setup GEMMs)
// ---------------------------------------------------------------------------
__global__ __launch_bounds__(256) void gemm_sq(const bf16* __restrict__ A,
        const bf16* __restrict__ Btm, bf16* __restrict__ Pout, bf16* __restrict__ Tout)
{
    TILE_PROLOGUE
    const int R0 = blockIdx.y * 128;
    const int C0 = blockIdx.x * 128;
    for (int k0 = 0; k0 < DIM; k0 += 64) {
        {
            int r = tid >> 3; const int c = (tid & 7) * 8;
            #pragma unroll
            for (int p = 0; p < 4; ++p, r += 32)
                *(uint4*)&As[r][c] = *(const uint4*)(A + (size_t)(R0 + r)*DIM + k0 + c);
        }
        STAGE_B(Btm, C0)
        TILE_MFMA
    }
    #pragma unroll
    for (int i = 0; i < 4; ++i) {
        const int rowb = R0 + wm + i*16 + quad*4;
        #pragma unroll
        for (int j = 0; j < 4; ++j) {
            const int cc = C0 + wn + j*16 + cn;
            #pragma unroll
            for (int rr = 0; rr < 4; ++rr) {
                const float v = acc[i][j][rr];
                Pout[(size_t)(rowb + rr)*DIM + cc] = __float2bfloat16(v);
                Tout[(size_t)cc*DIM + rowb + rr]  = __float2bfloat16(v);
            }
        }
    }
}

__global__ __launch_bounds__(256) void gemm_row0(const void* __restrict__ X,
        const bf16* __restrict__ WiT, const float* __restrict__ bvec,
        const int* __restrict__ flagp, float* __restrict__ U0)
{
    const int f32 = *flagp;
    TILE_PROLOGUE
    const int C0 = blockIdx.x * 128;
    for (int k0 = 0; k0 < DIM; k0 += 64) {
        {
            int r = tid >> 3; const int c = (tid & 7) * 8;
            #pragma unroll
            for (int p = 0; p < 4; ++p, r += 32) {
                const size_t base = (size_t)r*S_LEN*DIM + k0 + c;
                STAGE_A_IN(X, base)
            }
        }
        STAGE_B(WiT, C0)
        TILE_MFMA
    }
    #pragma unroll
    for (int i = 0; i < 4; ++i) {
        const int rowb = wm + i*16 + quad*4;
        #pragma unroll
        for (int j = 0; j < 4; ++j) {
            const int cc = C0 + wn + j*16 + cn;
            const float bb = bvec[cc];
            #pragma unroll
            for (int rr = 0; rr < 4; ++rr)
                U0[(size_t)(rowb + rr)*DIM + cc] = acc[i][j][rr] + bb;
        }
    }
}

__global__ __launch_bounds__(256) void gemm_v0(const float* __restrict__ U0,
        const bf16* __restrict__ T0, const float* __restrict__ dvec, float* __restrict__ V0)
{
    TILE_PROLOGUE
    const int C0 = blockIdx.x * 128;
    for (int k0 = 0; k0 < DIM; k0 += 64) {
        {
            int r = tid >> 3; const int c = (tid & 7) * 8;
            #pragma unroll
            for (int p = 0; p < 4; ++p, r += 32) {
                __align__(16) unsigned short w[8];
                #pragma unroll
                for (int q = 0; q < 8; ++q)
                    w[q] = f2bu(U0[(size_t)r*DIM + k0 + c + q] - dvec[k0 + c + q]);
                *(uint4*)&As[r][c] = *(const uint4*)w;
            }
        }
        STAGE_B(T0, C0)
        TILE_MFMA
    }
    #pragma unroll
    for (int i = 0; i < 4; ++i) {
        const int rowb = wm + i*16 + quad*4;
        #pragma unroll
        for (int j = 0; j < 4; ++j) {
            const int cc = C0 + wn + j*16 + cn;
            #pragma unroll
            for (int rr = 0; rr < 4; ++rr) {
                const size_t off = (size_t)(rowb + rr)*DIM + cc;
                V0[off] = acc[i][j][rr] + U0[off];
            }
        }
    }
}

// ---------------------------------------------------------------------------
// gemm_big v5: TLP-first geometry. 64x128 tile, 4 waves (2Mx2N: 32x64/wave),
// BK=64, dbuf LDS = 48 KB -> 3 blocks/CU (12 waves/CU). ONE barrier per
// K-tile: [stage kt+1 -> buf^1 | ds_read kt | MFMA | vmcnt(0) | barrier].
// Buffer-overwrite safe: all reads of buf^1 completed before prev barrier.
// Same verified swizzle involution (pre-swizzled source col + XOR read).
// MODE 2: xf pass — A = Abf[row], residual = Rf[cc] (bvec)
// MODE 1: level 1 — t==0 -> A1[b], t==1 -> V0b[b], else Abf[row-1]; resid Rf[off]
// MODE 0: level s — t>=shift -> Abf[row-shift] else Zr; resid Rf[off]
// Output: fp32 Of + bf16 Ob dual store, or d_out via flag when TO_OUT.
// Bit-identical math to rounds 1-4.
// ---------------------------------------------------------------------------
template<int MODE, bool TO_OUT>
__global__ __launch_bounds__(256, 3) void gemm_big(
        const bf16* __restrict__ Abf, const bf16* __restrict__ A1,
        const bf16* __restrict__ V0b, const bf16* __restrict__ Zr,
        const bf16* __restrict__ Bt,  const float* __restrict__ Rf,
        float* __restrict__ Of, bf16* __restrict__ Ob,
        void* __restrict__ Oout, size_t eoff, const int* __restrict__ flagp,
        const int shift)
{
    __shared__ __align__(16) unsigned short As[2][64*64];    // 16 KB
    __shared__ __align__(16) unsigned short Bs[2][128*64];   // 32 KB
    const int tid  = threadIdx.x;
    const int lane = tid & 63;
    const int w    = tid >> 6;                  // 0..3
    // XCD-grouped decode: 4 col-blocks sharing an A-panel stay adjacent
    const int nb = gridDim.x;                   // (CR/64)*4, %8==0
    const int p0 = blockIdx.x;
    const int L  = (p0 & 7) * (nb >> 3) + (p0 >> 3);
    const int bx = L & 3, by = L >> 2;
    const int R0 = by * 64, C0 = bx * 128;
    const int wm = (w & 1) * 32;                // 2 row-groups of 32
    const int wn = (w >> 1) * 64;               // 2 col-groups of 64
    const int cn = lane & 15;
    const int quad = lane >> 4;
    f32x4 acc[2][4];
    #pragma unroll
    for (int i = 0; i < 2; ++i)
        #pragma unroll
        for (int j = 0; j < 4; ++j) acc[i][j] = (f32x4){0.f,0.f,0.f,0.f};

    // staging: lines of 32 rows x 64 k (4 KB). A: 2 lines, B: 4 lines.
    const int lr  = w*8 + (lane >> 3);                    // 0..31 row-in-line
    const int lcb = ((lane & 7) ^ (lane >> 3)) * 8;       // pre-swizzled col
    const int ldst = w * 512;                             // ushort offset in line
    const bf16* aln[2];
    const bf16* bln[4];
    #pragma unroll
    for (int l = 0; l < 2; ++l) {
        const int grow = R0 + l*32 + lr;
        const bf16* a;
        if (MODE == 2) {
            a = Abf + (size_t)grow*DIM;
        } else if (MODE == 1) {
            const int t = grow & (S_LEN - 1);
            if      (t == 0) a = A1  + (size_t)(grow >> 9)*DIM;
            else if (t == 1) a = V0b + (size_t)(grow >> 9)*DIM;
            else             a = Abf + (size_t)(grow - 1)*DIM;
        } else {
            const int t = grow & (S_LEN - 1);
            a = (t >= shift) ? (Abf + (size_t)(grow - shift)*DIM) : Zr;
        }
        aln[l] = a + lcb;
    }
    #pragma unroll
    for (int l = 0; l < 4; ++l)
        bln[l] = Bt + (size_t)(C0 + l*32 + lr)*DIM + lcb;

#define STAGE(BUF, KN)                                                         \
    {                                                                          \
        gld16(aln[0] + (KN), &As[BUF][0*2048 + ldst]);                         \
        gld16(aln[1] + (KN), &As[BUF][1*2048 + ldst]);                         \
        gld16(bln[0] + (KN), &Bs[BUF][0*2048 + ldst]);                         \
        gld16(bln[1] + (KN), &Bs[BUF][1*2048 + ldst]);                         \
        gld16(bln[2] + (KN), &Bs[BUF][2*2048 + ldst]);                         \
        gld16(bln[3] + (KN), &Bs[BUF][3*2048 + ldst]);                         \
    }

    // prologue: tile 0 -> buf 0
    STAGE(0, 0)
    asm volatile("s_waitcnt vmcnt(0)" ::: "memory");
    __builtin_amdgcn_s_barrier();

    #pragma unroll
    for (int kt = 0; kt < 8; ++kt) {
        const int cur = kt & 1;
        if (kt < 7) STAGE(cur ^ 1, (kt + 1) * 64)
        // ds_read 12 frags of tile kt (compiler inserts lgkmcnt waits)
        short8 af[2][2], bfr[4][2];
        #pragma unroll
        for (int i = 0; i < 2; ++i) {
            af[i][0] = lds_frag(&As[cur][0], wm + i*16 + cn,      quad*8);
            af[i][1] = lds_frag(&As[cur][0], wm + i*16 + cn, 32 + quad*8);
        }
        #pragma unroll
        for (int j = 0; j < 4; ++j) {
            bfr[j][0] = lds_frag(&Bs[cur][0], wn + j*16 + cn,      quad*8);
            bfr[j][1] = lds_frag(&Bs[cur][0], wn + j*16 + cn, 32 + quad*8);
        }
        __builtin_amdgcn_s_setprio(1);
        #pragma unroll
        for (int i = 0; i < 2; ++i)
            #pragma unroll
            for (int j = 0; j < 4; ++j) {
                acc[i][j] = __builtin_amdgcn_mfma_f32_16x16x32_bf16(af[i][0], bfr[j][0], acc[i][j], 0, 0, 0);
                acc[i][j] = __builtin_amdgcn_mfma_f32_16x16x32_bf16(af[i][1], bfr[j][1], acc[i][j], 0, 0, 0);
            }
        __builtin_amdgcn_s_setprio(0);
        // drain this iteration's 6 staging loads, then release both buffers
        asm volatile("s_waitcnt vmcnt(0)" ::: "memory");
        __builtin_amdgcn_s_barrier();
    }
#undef STAGE

    const int f32o = TO_OUT ? *flagp : 0;
    #pragma unroll
    for (int i = 0; i < 2; ++i) {
        const int rowb = R0 + wm + i*16 + quad*4;
        #pragma unroll
        for (int j = 0; j < 4; ++j) {
            const int cc = C0 + wn + j*16 + cn;
            #pragma unroll
            for (int rr = 0; rr < 4; ++rr) {
                const size_t off = (size_t)(rowb + rr)*DIM + cc;
                const float res = (MODE == 2) ? Rf[cc] : Rf[off];
                const float v = acc[i][j][rr] + res;
                if (TO_OUT) {
                    if (f32o) ((float*)Oout)[eoff + off] = v;
                    else      ((bf16*)Oout)[eoff + off]  = __float2bfloat16(v);
                } else {
                    Of[off] = v;
                    Ob[off] = __float2bfloat16(v);
                }
            }
        }
    }
}

// final_state[b,:] = outputs[b, len_b - 1, :]
__global__ void gather_final(void* __restrict__ out, const int* __restrict__ lens,
                             const int* __restrict__ flagp)
{
    const int f32 = *flagp;
    const int idx = blockIdx.x * 256 + threadIdx.x;
    const int b = idx >> 9, n = idx & 511;
    int L = lens[b];
    if (L < 1) L = 1;
    if (L > S_LEN) L = S_LEN;
    const size_t src = ((size_t)b*S_LEN + (L - 1))*DIM + n;
    const size_t dst = (size_t)ROWS*DIM + idx;
    if (f32) ((float*)out)[dst] = ((const float*)out)[src];
    else     ((bf16*)out)[dst]  = ((const bf16*)out)[src];
}

// ---------------------------------------------------------------------------
extern "C" void kernel_launch(void* const* d_in, const int* in_sizes, int n_in,
                              void* d_out, int out_size, void* d_ws, size_t ws_size,
                              hipStream_t stream)
{
    const void* X  = d_in[0];
    const void* Wi = d_in[1];
    const void* bi = d_in[2];
    // d_in[3..6] = Wq, bq, Wk, bk — dead (softmax over singleton axis == 1)
    const void* Wv = d_in[7];
    const void* bv = d_in[8];
    const void* Wo = d_in[9];
    const void* bo = d_in[10];
    const int* lens = (const int*)d_in[11];
    char* ws = (char*)d_ws;

    // ---- fixed workspace layout ----
    const size_t MATB = (size_t)DIM * DIM * sizeof(bf16);    // 524288
    bf16* WiT = (bf16*)(ws + 0*MATB);
    bf16* WoT = (bf16*)(ws + 1*MATB);
    bf16* Wvb = (bf16*)(ws + 2*MATB);
    bf16* S2  = (bf16*)(ws + 3*MATB);   // W, then W^4
    bf16* S3  = (bf16*)(ws + 4*MATB);   // W^2, then W^8
    bf16* T0  = (bf16*)(ws + 5*MATB);   // W^T
    bf16* T1  = (bf16*)(ws + 6*MATB);   // (W^2)^T
    bf16* T2  = (bf16*)(ws + 7*MATB);   // (W^4)^T
    bf16* T3  = (bf16*)(ws + 8*MATB);   // (W^8)^T
    size_t off = 9*MATB;
    float* dvec = (float*)(ws + off); off += 2048;
    float* bvec = (float*)(ws + off); off += 2048;
    int*   flag = (int*)  (ws + off); off += 256;
    float* U0   = (float*)(ws + off); off += (size_t)BATCH*DIM*4;  // 262144
    float* V0   = (float*)(ws + off); off += (size_t)BATCH*DIM*4;
    bf16*  A1   = (bf16*) (ws + off); off += (size_t)BATCH*DIM*2;  // 131072
    bf16*  V0b  = (bf16*) (ws + off); off += (size_t)BATCH*DIM*2;
    bf16*  Zr   = (bf16*) (ws + off); off += 1024;
    off = (off + 1023) & ~(size_t)1023;
    char* dyn = ws + off;
    const size_t avail = ws_size > off ? ws_size - off : 0;

    // per-chunk: xbf (CR*1024) + Uf (CR*2048) + Ub (CR*1024) + Vf (CR*2048) + Vb (CR*1024)
    int CR = 512;
    for (long cr = 65536; cr >= 512; cr >>= 1)
        if ((size_t)cr * 7168 <= avail) { CR = (int)cr; break; }

    bf16*  xbf = (bf16*) dyn;
    float* Uf  = (float*)(dyn + (size_t)CR*1024);
    bf16*  Ub  = (bf16*) (dyn + (size_t)CR*3072);
    float* Vf  = (float*)(dyn + (size_t)CR*4096);
    bf16*  Vb  = (bf16*) (dyn + (size_t)CR*6144);

    detect_dtype<<<1, 256, 0, stream>>>((const unsigned int*)X, flag);
    conv_tr<<<dim3(16,16), dim3(32,8), 0, stream>>>(Wi, WiT, flag);
    conv_tr<<<dim3(16,16), dim3(32,8), 0, stream>>>(Wo, WoT, flag);
    conv_cp<<<1024, 256, 0, stream>>>(Wv, Wvb, flag);
    cvec_kernel<<<128, 256, 0, stream>>>(WoT, bv, bo, bi, flag, dvec, bvec);
    gemm_sq<<<dim3(4,4), 256, 0, stream>>>(Wvb, WoT, S2, T0);   // W
    gemm_sq<<<dim3(4,4), 256, 0, stream>>>(S2, T0, S3, T1);     // W^2
    gemm_sq<<<dim3(4,4), 256, 0, stream>>>(S3, T1, S2, T2);     // W^4
    gemm_sq<<<dim3(4,4), 256, 0, stream>>>(S2, T2, S3, T3);     // W^8
    gemm_row0<<<dim3(4,1), 256, 0, stream>>>(X, WiT, bvec, flag, U0);
    gemm_v0<<<dim3(4,1), 256, 0, stream>>>(U0, T0, dvec, V0);
    prep_aux<<<256, 256, 0, stream>>>(U0, V0, dvec, A1, V0b, Zr);

    const int NC = ROWS / CR;
    const int nb = (CR / 64) * 4;   // 64-row tiles x 4 col-blocks
    for (int c = 0; c < NC; ++c) {
        const size_t eoff = (size_t)c*CR*DIM;
        const size_t boff = (size_t)(c*(CR/S_LEN))*DIM;
        conv_x<<<CR/4, 256, 0, stream>>>(X, eoff, xbf, flag);
        gemm_big<2,false><<<nb, 256, 0, stream>>>(xbf, nullptr, nullptr, Zr,
                WiT, bvec, Uf, Ub, nullptr, 0, flag, 0);
        gemm_big<1,false><<<nb, 256, 0, stream>>>(Ub, A1 + boff, V0b + boff, Zr,
                T0, Uf, Vf, Vb, nullptr, 0, flag, 1);
        gemm_big<0,false><<<nb, 256, 0, stream>>>(Vb, nullptr, nullptr, Zr,
                T1, Vf, Uf, Ub, nullptr, 0, flag, 2);
        gemm_big<0,false><<<nb, 256, 0, stream>>>(Ub, nullptr, nullptr, Zr,
                T2, Uf, Vf, Vb, nullptr, 0, flag, 4);
        gemm_big<0,true ><<<nb, 256, 0, stream>>>(Vb, nullptr, nullptr, Zr,
                T3, Vf, nullptr, nullptr, d_out, eoff, flag, 8);
    }
    gather_final<<<256, 256, 0, stream>>>(d_out, lens, flag);
}